// Round 17
// baseline (221.093 us; speedup 1.0000x reference)
//
#include <hip/hip_runtime.h>

#define DMODEL 1024
#define DKH 64
#define NH 16
#define DFF 4096
#define BB 2
#define TT 2048
#define ROWS (BB*TT)      // 4096
#define QKVN (3*DMODEL)   // 3072
#define QSCALE 0.18033688011112042f   // 0.125 * log2(e)

typedef unsigned short ushort_t;
typedef __attribute__((ext_vector_type(8))) short s8v;
typedef __attribute__((ext_vector_type(4))) float f4v;
typedef __attribute__((ext_vector_type(4))) unsigned short us4v;

typedef const void __attribute__((address_space(1)))* GPTR;
typedef void __attribute__((address_space(3)))* SPTR;

__device__ __forceinline__ float bf2f(ushort_t u) {
  return __uint_as_float(((unsigned int)u) << 16);
}
__device__ __forceinline__ ushort_t f2bf(float f) {
  unsigned int u = __float_as_uint(f);
  u += 0x7fffu + ((u >> 16) & 1u);
  return (ushort_t)(u >> 16);
}
__device__ __forceinline__ void gload16(const void* g, void* l) {
  __builtin_amdgcn_global_load_lds((GPTR)g, (SPTR)l, 16, 0, 0);
}

// ---------------- conversion kernels ----------------
__global__ __launch_bounds__(256) void cvt_f32_bf16(const float* __restrict__ in,
                                                    ushort_t* __restrict__ out, int n4) {
  int i = blockIdx.x * 256 + threadIdx.x;
  if (i >= n4) return;
  float4 v = ((const float4*)in)[i];
  us4v o;
  o.x = f2bf(v.x); o.y = f2bf(v.y); o.z = f2bf(v.z); o.w = f2bf(v.w);
  ((us4v*)out)[i] = o;
}

// Wq/Wk/Wv: three 1024x1024 f32 -> WqkvT [3][1024][1024] bf16 (transposed)
__global__ __launch_bounds__(256) void trans_qkv(const float* __restrict__ w0,
                                                 const float* __restrict__ w1,
                                                 const float* __restrict__ w2,
                                                 ushort_t* __restrict__ out) {
  __shared__ float tile[32][33];
  const float* in = (blockIdx.z == 0) ? w0 : (blockIdx.z == 1) ? w1 : w2;
  ushort_t* dst = out + (size_t)blockIdx.z * DMODEL * DMODEL;
  int bx = blockIdx.x * 32, by = blockIdx.y * 32;
  int tx = threadIdx.x, ty = threadIdx.y;
#pragma unroll
  for (int i = 0; i < 32; i += 8)
    tile[ty + i][tx] = in[(size_t)(by + ty + i) * DMODEL + bx + tx];
  __syncthreads();
#pragma unroll
  for (int i = 0; i < 32; i += 8)
    dst[(size_t)(bx + ty + i) * DMODEL + by + tx] = f2bf(tile[tx][ty + i]);
}

// W1 [1024,4096] -> W1T [4096,1024]; W2 [4096,1024] -> W2T [1024,4096]
__global__ __launch_bounds__(256) void trans_ffn(const float* __restrict__ W1,
                                                 const float* __restrict__ W2,
                                                 ushort_t* __restrict__ W1T,
                                                 ushort_t* __restrict__ W2T) {
  __shared__ float tile[32][33];
  const int z = blockIdx.z;
  const float* in = z ? W2 : W1;
  ushort_t* dst = z ? W2T : W1T;
  const int R = z ? DFF : DMODEL;      // in rows
  const int C = z ? DMODEL : DFF;      // in cols
  int bx = (z ? blockIdx.y : blockIdx.x) * 32;   // col-block
  int by = (z ? blockIdx.x : blockIdx.y) * 32;   // row-block
  int tx = threadIdx.x, ty = threadIdx.y;
#pragma unroll
  for (int i = 0; i < 32; i += 8)
    tile[ty + i][tx] = in[(size_t)(by + ty + i) * C + bx + tx];
  __syncthreads();
#pragma unroll
  for (int i = 0; i < 32; i += 8)
    dst[(size_t)(bx + ty + i) * R + by + tx] = f2bf(tile[tx][ty + i]);
}

__global__ void concat_bias(const float* __restrict__ a, const float* __restrict__ b,
                            const float* __restrict__ c, float* __restrict__ o) {
  int i = blockIdx.x * 256 + threadIdx.x;
  if (i < 1024) { o[i] = a[i]; o[1024 + i] = b[i]; o[2048 + i] = c[i]; }
}

// V block of QKV (bf16) -> VT[bh][d=64][t=TT] bf16
__global__ __launch_bounds__(256) void vtrans(const ushort_t* __restrict__ QKV,
                                              ushort_t* __restrict__ VT) {
  __shared__ ushort_t tile[32][66];   // [t-local][d], +2 pad
  const int t0 = blockIdx.x * 32;
  const int bh = blockIdx.y;
  const int b = bh >> 4, h = bh & 15;
  const int tx = threadIdx.x, ty = threadIdx.y;   // (32,8)
  const ushort_t* src = QKV + ((size_t)b * TT + t0) * QKVN + 2 * DMODEL + h * 64;
#pragma unroll
  for (int i = 0; i < 4; ++i) {
    int r = ty + i * 8;
    *(unsigned int*)&tile[r][tx * 2] = *(const unsigned int*)(src + (size_t)r * QKVN + tx * 2);
  }
  __syncthreads();
  unsigned int* dst = (unsigned int*)(VT + (size_t)bh * 64 * TT);
#pragma unroll
  for (int i = 0; i < 4; ++i) {
    int d = ty + i * 8 + (tx >> 4) * 32;   // 0..63
    int p = tx & 15;                        // t-pair within tile
    unsigned int lo = tile[2 * p][d], hi = tile[2 * p + 1][d];
    dst[(size_t)d * (TT / 2) + (t0 >> 1) + p] = lo | (hi << 16);
  }
}

// ---------------- GEMM 128x128, BK=64, dbuf, 1 barrier-pair/tile (r11-proven) ----------------
// MODE 0: +bias. MODE 1: +bias+relu. MODE 2: split-K partial (no bias).
// MODE 3: +bias then scale cols<1024 by QSCALE (QKV: pre-scale Q for exp2).
template<int MODE>
__global__ __launch_bounds__(256) void gemm128(const ushort_t* __restrict__ A,
                                               const ushort_t* __restrict__ BT,
                                               const float* __restrict__ bias,
                                               ushort_t* __restrict__ C,
                                               int M, int N, int Kstride, int Kloop,
                                               int nbx, int tiles_per_k) {
  __shared__ __align__(16) ushort_t As[2][128 * 64];   // 16 KB each
  __shared__ __align__(16) ushort_t Bs[2][128 * 64];
  const int nwg = gridDim.x;
  const int wg = blockIdx.x;
  const int cpx = nwg >> 3;                    // nwg % 8 == 0
  const int swz = (wg & 7) * cpx + (wg >> 3);  // XCD-aware (T1)
  const int ks = swz / tiles_per_k;
  const int tile = swz % tiles_per_k;
  const int bx = tile % nbx, by = tile / nbx;
  const int m0 = by * 128, n0 = bx * 128;
  const size_t kbase = (size_t)ks * Kloop;
  const int tid = threadIdx.x;
  const int w = tid >> 6, l = tid & 63, lr = l & 15, lg = l >> 4;
  const int wm = w >> 1, wn = w & 1;

  const int sr = tid >> 3;
  const int scol = (((tid & 7) ^ ((tid >> 3) & 7)) << 3);

  auto stageA = [&](int kt, int buf) {
#pragma unroll
    for (int s = 0; s < 4; ++s)
      gload16(A + (size_t)(m0 + s * 32 + sr) * Kstride + kbase + kt * 64 + scol,
              (char*)&As[buf][0] + s * 4096 + tid * 16);
  };
  auto stageB = [&](int kt, int buf) {
#pragma unroll
    for (int s = 0; s < 4; ++s)
      gload16(BT + (size_t)(n0 + s * 32 + sr) * Kstride + kbase + kt * 64 + scol,
              (char*)&Bs[buf][0] + s * 4096 + tid * 16);
  };

  const int rsw = (lr & 7) << 4;
  auto ldA = [&](int buf, int m, int kk) -> s8v {
    return *(const s8v*)((const char*)&As[buf][0] +
                         (wm * 64 + m * 16 + lr) * 128 + ((kk * 64 + lg * 16) ^ rsw));
  };
  auto ldB = [&](int buf, int n, int kk) -> s8v {
    return *(const s8v*)((const char*)&Bs[buf][0] +
                         (wn * 64 + n * 16 + lr) * 128 + ((kk * 64 + lg * 16) ^ rsw));
  };

  f4v acc[4][4] = {};
  const int NT = Kloop >> 6;

  stageA(0, 0); stageB(0, 0);
  asm volatile("s_waitcnt vmcnt(0)" ::: "memory");
  __builtin_amdgcn_sched_barrier(0);
  __builtin_amdgcn_s_barrier();

  for (int t = 0; t < NT; ++t) {
    const int cb = t & 1, nb = cb ^ 1;
    if (t + 1 < NT) { stageA(t + 1, nb); stageB(t + 1, nb); }
    s8v af[2][4], bfr[2][4];
#pragma unroll
    for (int m = 0; m < 4; ++m) { af[0][m] = ldA(cb, m, 0); af[1][m] = ldA(cb, m, 1); }
#pragma unroll
    for (int n = 0; n < 4; ++n) { bfr[0][n] = ldB(cb, n, 0); bfr[1][n] = ldB(cb, n, 1); }
    __builtin_amdgcn_s_setprio(1);
#pragma unroll
    for (int m = 0; m < 4; ++m)
#pragma unroll
      for (int n = 0; n < 4; ++n) {
        acc[m][n] = __builtin_amdgcn_mfma_f32_16x16x32_bf16(af[0][m], bfr[0][n], acc[m][n], 0, 0, 0);
        acc[m][n] = __builtin_amdgcn_mfma_f32_16x16x32_bf16(af[1][m], bfr[1][n], acc[m][n], 0, 0, 0);
      }
    __builtin_amdgcn_s_setprio(0);
    if (t + 1 < NT) asm volatile("s_waitcnt vmcnt(0)" ::: "memory");
    __builtin_amdgcn_sched_barrier(0);
    __builtin_amdgcn_s_barrier();
  }

  ushort_t* Cp = (MODE == 2) ? (C + (size_t)ks * M * N) : C;
#pragma unroll
  for (int n = 0; n < 4; ++n) {
    int col = n0 + wn * 64 + n * 16 + lr;
    float bv = (MODE == 2) ? 0.f : bias[col];
    float sc = (MODE == 3 && col < DMODEL) ? QSCALE : 1.f;
#pragma unroll
    for (int m = 0; m < 4; ++m) {
      int row = m0 + wm * 64 + m * 16 + lg * 4;
#pragma unroll
      for (int j = 0; j < 4; ++j) {
        float v = acc[m][n][j] + bv;
        if (MODE == 1) v = fmaxf(v, 0.f);
        if (MODE == 3) v *= sc;
        Cp[(size_t)(row + j) * N + col] = f2bf(v);
      }
    }
  }
}

// ---------------- causal flash attention (v11: uniform paired blocks) ----------------
// Block (bh, bx) processes q-tiles {31-bx, bx} SEQUENTIALLY: exactly 33
// KV-tile bodies per block -> every CU does 66 bodies regardless of the
// (undefined) block->CU assignment. Grid 512, all co-resident, zero tail.
// (r15 lesson: mappings that assume a dispatch pattern fail; uniformity
// per block is assignment-independent.) v10 internals: exp2 w/ pre-scaled
// Q, cvt_pk packing, K dbuf + V single-buffer counted-vmcnt pipeline.
__global__ __launch_bounds__(256) void attn_kernel(const ushort_t* __restrict__ QKV,
                                                   const ushort_t* __restrict__ VT,
                                                   ushort_t* __restrict__ O) {
  const int bh = blockIdx.x;             // 0..31
  const int bxp = blockIdx.y;            // 0..15
  const int b = bh >> 4, h = bh & 15;
  const int tid = threadIdx.x;
  const int w = tid >> 6, l = tid & 63;
  const int lr = l & 15, lg = l >> 4;

  __shared__ __align__(16) ushort_t Ksh[2][64 * 64];   // [k][d], chunk-swizzled
  __shared__ __align__(16) ushort_t Vsh[64 * 64];      // [d][k], single buffer
  __shared__ __align__(16) ushort_t Psh[4][16 * 72];   // per-wave [q][k], 144B rows

  const size_t RS = QKVN;
  const ushort_t* Qb = QKV + (size_t)b * TT * RS + h * 64;
  const ushort_t* Kb = Qb + DMODEL;
  const ushort_t* Vb = VT + (size_t)bh * 64 * TT;

  const int sr8 = l >> 3, sc = l & 7;

  auto stageK = [&](int kt, int buf) {
#pragma unroll
    for (int s = 0; s < 2; ++s) {
      int r = s * 32 + w * 8 + sr8;
      gload16(Kb + (size_t)(kt * 64 + r) * RS + ((sc ^ (r & 7)) << 3),
              (char*)&Ksh[buf][0] + (s * 32 + w * 8) * 128 + l * 16);
    }
  };
  auto stageV = [&](int kt) {
#pragma unroll
    for (int s = 0; s < 2; ++s) {
      int r = s * 32 + w * 8 + sr8;
      gload16(Vb + (size_t)r * TT + kt * 64 + ((sc ^ (r & 7)) << 3),
              (char*)&Vsh[0] + (s * 32 + w * 8) * 128 + l * 16);
    }
  };

#pragma unroll 1
  for (int pass = 0; pass < 2; ++pass) {
    const int qt = pass ? bxp : (31 - bxp);
    const int nkt = qt + 1;
    s8v qf[2];
    {
      const ushort_t* qr = Qb + (size_t)(qt * 64 + w * 16 + lr) * RS + lg * 8;
      qf[0] = *(const s8v*)qr;
      qf[1] = *(const s8v*)(qr + 32);
    }
    f4v acc[4] = {};
    float lrow = 0.f;

    stageK(0, 0);   // safe: prev pass ended with all LDS reads fenced + 0 loads in flight
    for (int kt = 0; kt < nkt; ++kt) {
      const int cb = kt & 1;
      const bool last = (kt + 1 >= nkt);
      stageV(kt);
      if (!last) {
        stageK(kt + 1, cb ^ 1);
        asm volatile("s_waitcnt vmcnt(4)" ::: "memory");   // K(kt) landed
      } else {
        asm volatile("s_waitcnt vmcnt(2)" ::: "memory");   // K(kt) landed
      }
      __builtin_amdgcn_sched_barrier(0);
      __builtin_amdgcn_s_barrier();

      // ---- QK^T (swapped: mfma(K,Q)) + exp2 + P staging (cvt_pk packing) ----
      float ps = 0.f;
#pragma unroll
      for (int c = 0; c < 4; ++c) {
        f4v a = {};
        __builtin_amdgcn_s_setprio(1);
#pragma unroll
        for (int kk = 0; kk < 2; ++kk) {
          int rr = c * 16 + lr;
          int byte_ = (rr * 128 + kk * 64 + lg * 16) ^ ((rr & 7) << 4);
          s8v kf = *(const s8v*)((const char*)&Ksh[cb][0] + byte_);
          a = __builtin_amdgcn_mfma_f32_16x16x32_bf16(kf, qf[kk], a, 0, 0, 0);
        }
        __builtin_amdgcn_s_setprio(0);
        float e[4];
#pragma unroll
        for (int j = 0; j < 4; ++j) {
          e[j] = exp2f(a[j]);   // Q pre-scaled by 0.125*log2(e)
          if (last && (c * 16 + lg * 4 + j > w * 16 + lr)) e[j] = 0.f;
          ps += e[j];
        }
        unsigned int pk0, pk1;
        asm("v_cvt_pk_bf16_f32 %0, %1, %2" : "=v"(pk0) : "v"(e[0]), "v"(e[1]));
        asm("v_cvt_pk_bf16_f32 %0, %1, %2" : "=v"(pk1) : "v"(e[2]), "v"(e[3]));
        *(uint2*)((char*)&Psh[w][0] + lr * 144 + (c * 16 + lg * 4) * 2) = make_uint2(pk0, pk1);
      }
      s8v pa[2];
      pa[0] = *(const s8v*)((const char*)&Psh[w][0] + lr * 144 + lg * 16);
      pa[1] = *(const s8v*)((const char*)&Psh[w][0] + lr * 144 + 64 + lg * 16);

      if (!last) {
        asm volatile("s_waitcnt vmcnt(2)" ::: "memory");   // V(kt) landed
      } else {
        asm volatile("s_waitcnt vmcnt(0)" ::: "memory");
      }
      __builtin_amdgcn_sched_barrier(0);
      __builtin_amdgcn_s_barrier();

      // ---- O += P @ V ----
      __builtin_amdgcn_s_setprio(1);
#pragma unroll
      for (int ks = 0; ks < 2; ++ks)
#pragma unroll
        for (int d = 0; d < 4; ++d) {
          int row = d * 16 + lr;
          int byte_ = (row * 128 + ks * 64 + lg * 16) ^ ((row & 7) << 4);
          s8v vf = *(const s8v*)((const char*)&Vsh[0] + byte_);
          acc[d] = __builtin_amdgcn_mfma_f32_16x16x32_bf16(pa[ks], vf, acc[d], 0, 0, 0);
        }
      __builtin_amdgcn_s_setprio(0);
      ps += __shfl_xor(ps, 16);
      ps += __shfl_xor(ps, 32);
      lrow += ps;
      __builtin_amdgcn_s_barrier();
    }

    float inv = 1.f / lrow;
    ushort_t* orow = O + ((size_t)b * TT + qt * 64 + w * 16) * DMODEL + h * 64;
#pragma unroll
    for (int j = 0; j < 4; ++j) {
      float invj = __shfl(inv, lg * 4 + j);
#pragma unroll
      for (int d = 0; d < 4; ++d)
        orow[(size_t)(lg * 4 + j) * DMODEL + d * 16 + lr] = f2bf(acc[d][j] * invj);
    }
  }
}

// ---------------- LN 1: y_bf16 = LN(x_f32 + 2*attn_bf16) ----------------
__global__ __launch_bounds__(256) void ln_kernel(const float* __restrict__ aptr,
                                                 const ushort_t* __restrict__ bptr,
                                                 const float* __restrict__ g,
                                                 const float* __restrict__ be,
                                                 ushort_t* __restrict__ yptr) {
  const int row = blockIdx.x;
  const int t = threadIdx.x;
  const int w = t >> 6, l = t & 63;
  const size_t base = (size_t)row * DMODEL + t * 4;
  float v[4];
  us4v bb = *(const us4v*)(bptr + base);
  float4 xa = *(const float4*)(aptr + base);
  v[0] = xa.x + 2.f * bf2f(bb.x);
  v[1] = xa.y + 2.f * bf2f(bb.y);
  v[2] = xa.z + 2.f * bf2f(bb.z);
  v[3] = xa.w + 2.f * bf2f(bb.w);
  float s = v[0] + v[1] + v[2] + v[3];
  float s2 = v[0] * v[0] + v[1] * v[1] + v[2] * v[2] + v[3] * v[3];
#pragma unroll
  for (int off = 1; off <= 32; off <<= 1) {
    s += __shfl_xor(s, off);
    s2 += __shfl_xor(s2, off);
  }
  __shared__ float red[2][4];
  if (l == 0) { red[0][w] = s; red[1][w] = s2; }
  __syncthreads();
  s = red[0][0] + red[0][1] + red[0][2] + red[0][3];
  s2 = red[1][0] + red[1][1] + red[1][2] + red[1][3];
  const float mu = s * (1.f / 1024.f);
  const float var = s2 * (1.f / 1024.f) - mu * mu;
  const float rstd = rsqrtf(var + 1e-5f);
  float4 g4 = *(const float4*)(g + t * 4);
  float4 be4 = *(const float4*)(be + t * 4);
  us4v o;
  o.x = f2bf((v[0] - mu) * rstd * g4.x + be4.x);
  o.y = f2bf((v[1] - mu) * rstd * g4.y + be4.y);
  o.z = f2bf((v[2] - mu) * rstd * g4.z + be4.z);
  o.w = f2bf((v[3] - mu) * rstd * g4.w + be4.w);
  *(us4v*)(yptr + base) = o;
}

// ---------------- LN 2 (fused split-K=2 reduce): out = LN(x1 + 2*(SUMpart + b2)) ----------------
__global__ __launch_bounds__(256) void ln2_kernel(const ushort_t* __restrict__ x1,
                                                  const ushort_t* __restrict__ part,
                                                  const float* __restrict__ b2,
                                                  const float* __restrict__ g,
                                                  const float* __restrict__ be,
                                                  float* __restrict__ y) {
  const int row = blockIdx.x;
  const int t = threadIdx.x;
  const int w = t >> 6, l = t & 63;
  const size_t base = (size_t)row * DMODEL + t * 4;
  us4v xa = *(const us4v*)(x1 + base);
  float f[4] = {0.f, 0.f, 0.f, 0.f};
#pragma unroll
  for (int ks = 0; ks < 2; ++ks) {
    us4v p = *(const us4v*)(part + (size_t)ks * ROWS * DMODEL + base);
    f[0] += bf2f(p.x); f[1] += bf2f(p.y); f[2] += bf2f(p.z); f[3] += bf2f(p.w);
  }
  float4 b2v = *(const float4*)(b2 + t * 4);
  float v[4];
  v[0] = bf2f(xa.x) + 2.f * (f[0] + b2v.x);
  v[1] = bf2f(xa.y) + 2.f * (f[1] + b2v.y);
  v[2] = bf2f(xa.z) + 2.f * (f[2] + b2v.z);
  v[3] = bf2f(xa.w) + 2.f * (f[3] + b2v.w);
  float s = v[0] + v[1] + v[2] + v[3];
  float s2 = v[0] * v[0] + v[1] * v[1] + v[2] * v[2] + v[3] * v[3];
#pragma unroll
  for (int off = 1; off <= 32; off <<= 1) {
    s += __shfl_xor(s, off);
    s2 += __shfl_xor(s2, off);
  }
  __shared__ float red[2][4];
  if (l == 0) { red[0][w] = s; red[1][w] = s2; }
  __syncthreads();
  s = red[0][0] + red[0][1] + red[0][2] + red[0][3];
  s2 = red[1][0] + red[1][1] + red[1][2] + red[1][3];
  const float mu = s * (1.f / 1024.f);
  const float var = s2 * (1.f / 1024.f) - mu * mu;
  const float rstd = rsqrtf(var + 1e-5f);
  float4 g4 = *(const float4*)(g + t * 4);
  float4 be4 = *(const float4*)(be + t * 4);
  float4 o;
  o.x = (v[0] - mu) * rstd * g4.x + be4.x;
  o.y = (v[1] - mu) * rstd * g4.y + be4.y;
  o.z = (v[2] - mu) * rstd * g4.z + be4.z;
  o.w = (v[3] - mu) * rstd * g4.w + be4.w;
  *(float4*)(y + base) = o;
}

// ---------------- launch ----------------
extern "C" void kernel_launch(void* const* d_in, const int* in_sizes, int n_in,
                              void* d_out, int out_size, void* d_ws, size_t ws_size,
                              hipStream_t stream) {
  const float* x   = (const float*)d_in[0];
  const float* Wq  = (const float*)d_in[2];
  const float* bq  = (const float*)d_in[3];
  const float* Wk  = (const float*)d_in[4];
  const float* bk  = (const float*)d_in[5];
  const float* Wv  = (const float*)d_in[6];
  const float* bv  = (const float*)d_in[7];
  const float* W1  = (const float*)d_in[8];
  const float* b1  = (const float*)d_in[9];
  const float* W2  = (const float*)d_in[10];
  const float* b2  = (const float*)d_in[11];
  const float* g1  = (const float*)d_in[12];
  const float* be1 = (const float*)d_in[13];
  const float* g2  = (const float*)d_in[14];
  const float* be2 = (const float*)d_in[15];
  float* out = (float*)d_out;

  char* ws = (char*)d_ws;
  size_t off = 0;
  auto alloc = [&](size_t bytes) {
    char* p = ws + off;
    off += (bytes + 255) & ~(size_t)255;
    return p;
  };
  ushort_t* xb    = (ushort_t*)alloc((size_t)ROWS * DMODEL * 2);
  ushort_t* WqkvT = (ushort_t*)alloc((size_t)QKVN * DMODEL * 2);
  ushort_t* W1T   = (ushort_t*)alloc((size_t)DFF * DMODEL * 2);
  ushort_t* W2T   = (ushort_t*)alloc((size_t)DMODEL * DFF * 2);
  ushort_t* QKV   = (ushort_t*)alloc((size_t)ROWS * QKVN * 2);      // 24 MB
  ushort_t* VTb   = (ushort_t*)alloc((size_t)BB * NH * 64 * TT * 2); // 8 MB
  ushort_t* attnb = (ushort_t*)alloc((size_t)ROWS * DMODEL * 2);
  ushort_t* x1b   = (ushort_t*)alloc((size_t)ROWS * DMODEL * 2);
  ushort_t* H1b   = (ushort_t*)alloc((size_t)ROWS * DFF * 2);
  float* qkvb     = (float*)alloc(QKVN * 4);
  // FFN2 split-K=2 bf16 partials (2 x 8 MB) overlay dead QKV region.
  ushort_t* part  = QKV;
  (void)ws_size; (void)in_sizes; (void)n_in; (void)out_size;

  dim3 b256(256);
  dim3 tb(32, 8);
  cvt_f32_bf16<<<ROWS * DMODEL / 4 / 256, b256, 0, stream>>>(x, xb, ROWS * DMODEL / 4);
  trans_qkv<<<dim3(32, 32, 3), tb, 0, stream>>>(Wq, Wk, Wv, WqkvT);
  trans_ffn<<<dim3(DFF / 32, DMODEL / 32, 2), tb, 0, stream>>>(W1, W2, W1T, W2T);
  concat_bias<<<4, b256, 0, stream>>>(bq, bk, bv, qkvb);

  // QKV: 32 M-tiles x 24 N-tiles = 768 blocks; MODE 3 pre-scales Q cols
  gemm128<3><<<dim3(768), b256, 0, stream>>>(xb, WqkvT, qkvb, QKV,
                                             ROWS, QKVN, DMODEL, DMODEL,
                                             QKVN / 128, 768);
  vtrans<<<dim3(TT / 32, BB * NH), tb, 0, stream>>>(QKV, VTb);
  // attn: uniform paired blocks -> grid (32 bh, 16 pairs) = 512
  attn_kernel<<<dim3(BB * NH, 16), b256, 0, stream>>>(QKV, VTb, attnb);
  ln_kernel<<<ROWS, b256, 0, stream>>>(x, attnb, g1, be1, x1b);
  // FFN1: 32 x 32 = 1024 blocks
  gemm128<1><<<dim3(1024), b256, 0, stream>>>(x1b, W1T, b1, H1b,
                                              ROWS, DFF, DMODEL, DMODEL,
                                              DFF / 128, 1024);
  // FFN2: split-K=2 -> 32x8 tiles x 2 slices = 512 blocks; bf16 partials
  gemm128<2><<<dim3(512), b256, 0, stream>>>(H1b, W2T, b2, part,
                                             ROWS, DMODEL, DFF, DFF / 2,
                                             DMODEL / 128, 256);
  ln2_kernel<<<ROWS, b256, 0, stream>>>(x1b, part, b2, g2, be2, out);
}

// Round 18
// 214.676 us; speedup vs baseline: 1.0299x; 1.0299x over previous
//
#include <hip/hip_runtime.h>

#define DMODEL 1024
#define DKH 64
#define NH 16
#define DFF 4096
#define BB 2
#define TT 2048
#define ROWS (BB*TT)      // 4096
#define QKVN (3*DMODEL)   // 3072
#define QSCALE 0.18033688011112042f   // 0.125 * log2(e)

typedef unsigned short ushort_t;
typedef __attribute__((ext_vector_type(8))) short s8v;
typedef __attribute__((ext_vector_type(4))) float f4v;
typedef __attribute__((ext_vector_type(4))) unsigned short us4v;

typedef const void __attribute__((address_space(1)))* GPTR;
typedef void __attribute__((address_space(3)))* SPTR;

__device__ __forceinline__ float bf2f(ushort_t u) {
  return __uint_as_float(((unsigned int)u) << 16);
}
__device__ __forceinline__ ushort_t f2bf(float f) {
  unsigned int u = __float_as_uint(f);
  u += 0x7fffu + ((u >> 16) & 1u);
  return (ushort_t)(u >> 16);
}
__device__ __forceinline__ void gload16(const void* g, void* l) {
  __builtin_amdgcn_global_load_lds((GPTR)g, (SPTR)l, 16, 0, 0);
}

// ---------------- conversion kernels ----------------
__global__ __launch_bounds__(256) void cvt_f32_bf16(const float* __restrict__ in,
                                                    ushort_t* __restrict__ out, int n4) {
  int i = blockIdx.x * 256 + threadIdx.x;
  if (i >= n4) return;
  float4 v = ((const float4*)in)[i];
  us4v o;
  o.x = f2bf(v.x); o.y = f2bf(v.y); o.z = f2bf(v.z); o.w = f2bf(v.w);
  ((us4v*)out)[i] = o;
}

// Wq/Wk/Wv: three 1024x1024 f32 -> WqkvT [3][1024][1024] bf16 (transposed)
__global__ __launch_bounds__(256) void trans_qkv(const float* __restrict__ w0,
                                                 const float* __restrict__ w1,
                                                 const float* __restrict__ w2,
                                                 ushort_t* __restrict__ out) {
  __shared__ float tile[32][33];
  const float* in = (blockIdx.z == 0) ? w0 : (blockIdx.z == 1) ? w1 : w2;
  ushort_t* dst = out + (size_t)blockIdx.z * DMODEL * DMODEL;
  int bx = blockIdx.x * 32, by = blockIdx.y * 32;
  int tx = threadIdx.x, ty = threadIdx.y;
#pragma unroll
  for (int i = 0; i < 32; i += 8)
    tile[ty + i][tx] = in[(size_t)(by + ty + i) * DMODEL + bx + tx];
  __syncthreads();
#pragma unroll
  for (int i = 0; i < 32; i += 8)
    dst[(size_t)(bx + ty + i) * DMODEL + by + tx] = f2bf(tile[tx][ty + i]);
}

// W1 [1024,4096] -> W1T [4096,1024]; W2 [4096,1024] -> W2T [1024,4096]
__global__ __launch_bounds__(256) void trans_ffn(const float* __restrict__ W1,
                                                 const float* __restrict__ W2,
                                                 ushort_t* __restrict__ W1T,
                                                 ushort_t* __restrict__ W2T) {
  __shared__ float tile[32][33];
  const int z = blockIdx.z;
  const float* in = z ? W2 : W1;
  ushort_t* dst = z ? W2T : W1T;
  const int R = z ? DFF : DMODEL;      // in rows
  const int C = z ? DMODEL : DFF;      // in cols
  int bx = (z ? blockIdx.y : blockIdx.x) * 32;   // col-block
  int by = (z ? blockIdx.x : blockIdx.y) * 32;   // row-block
  int tx = threadIdx.x, ty = threadIdx.y;
#pragma unroll
  for (int i = 0; i < 32; i += 8)
    tile[ty + i][tx] = in[(size_t)(by + ty + i) * C + bx + tx];
  __syncthreads();
#pragma unroll
  for (int i = 0; i < 32; i += 8)
    dst[(size_t)(bx + ty + i) * R + by + tx] = f2bf(tile[tx][ty + i]);
}

__global__ void concat_bias(const float* __restrict__ a, const float* __restrict__ b,
                            const float* __restrict__ c, float* __restrict__ o) {
  int i = blockIdx.x * 256 + threadIdx.x;
  if (i < 1024) { o[i] = a[i]; o[1024 + i] = b[i]; o[2048 + i] = c[i]; }
}

// V block of QKV (bf16) -> VT[bh][d=64][t=TT] bf16
__global__ __launch_bounds__(256) void vtrans(const ushort_t* __restrict__ QKV,
                                              ushort_t* __restrict__ VT) {
  __shared__ ushort_t tile[32][66];   // [t-local][d], +2 pad
  const int t0 = blockIdx.x * 32;
  const int bh = blockIdx.y;
  const int b = bh >> 4, h = bh & 15;
  const int tx = threadIdx.x, ty = threadIdx.y;   // (32,8)
  const ushort_t* src = QKV + ((size_t)b * TT + t0) * QKVN + 2 * DMODEL + h * 64;
#pragma unroll
  for (int i = 0; i < 4; ++i) {
    int r = ty + i * 8;
    *(unsigned int*)&tile[r][tx * 2] = *(const unsigned int*)(src + (size_t)r * QKVN + tx * 2);
  }
  __syncthreads();
  unsigned int* dst = (unsigned int*)(VT + (size_t)bh * 64 * TT);
#pragma unroll
  for (int i = 0; i < 4; ++i) {
    int d = ty + i * 8 + (tx >> 4) * 32;   // 0..63
    int p = tx & 15;                        // t-pair within tile
    unsigned int lo = tile[2 * p][d], hi = tile[2 * p + 1][d];
    dst[(size_t)d * (TT / 2) + (t0 >> 1) + p] = lo | (hi << 16);
  }
}

// ---------------- GEMM 128x128, BK=64, dbuf, 1 barrier-pair/tile (r11-proven) ----------------
// MODE 0: +bias. MODE 1: +bias+relu. MODE 2: split-K partial (no bias).
// MODE 3: +bias then scale cols<1024 by QSCALE (QKV: pre-scale Q for exp2).
template<int MODE>
__global__ __launch_bounds__(256) void gemm128(const ushort_t* __restrict__ A,
                                               const ushort_t* __restrict__ BT,
                                               const float* __restrict__ bias,
                                               ushort_t* __restrict__ C,
                                               int M, int N, int Kstride, int Kloop,
                                               int nbx, int tiles_per_k) {
  __shared__ __align__(16) ushort_t As[2][128 * 64];   // 16 KB each
  __shared__ __align__(16) ushort_t Bs[2][128 * 64];
  const int nwg = gridDim.x;
  const int wg = blockIdx.x;
  const int cpx = nwg >> 3;                    // nwg % 8 == 0
  const int swz = (wg & 7) * cpx + (wg >> 3);  // XCD-aware (T1)
  const int ks = swz / tiles_per_k;
  const int tile = swz % tiles_per_k;
  const int bx = tile % nbx, by = tile / nbx;
  const int m0 = by * 128, n0 = bx * 128;
  const size_t kbase = (size_t)ks * Kloop;
  const int tid = threadIdx.x;
  const int w = tid >> 6, l = tid & 63, lr = l & 15, lg = l >> 4;
  const int wm = w >> 1, wn = w & 1;

  const int sr = tid >> 3;
  const int scol = (((tid & 7) ^ ((tid >> 3) & 7)) << 3);

  auto stageA = [&](int kt, int buf) {
#pragma unroll
    for (int s = 0; s < 4; ++s)
      gload16(A + (size_t)(m0 + s * 32 + sr) * Kstride + kbase + kt * 64 + scol,
              (char*)&As[buf][0] + s * 4096 + tid * 16);
  };
  auto stageB = [&](int kt, int buf) {
#pragma unroll
    for (int s = 0; s < 4; ++s)
      gload16(BT + (size_t)(n0 + s * 32 + sr) * Kstride + kbase + kt * 64 + scol,
              (char*)&Bs[buf][0] + s * 4096 + tid * 16);
  };

  const int rsw = (lr & 7) << 4;
  auto ldA = [&](int buf, int m, int kk) -> s8v {
    return *(const s8v*)((const char*)&As[buf][0] +
                         (wm * 64 + m * 16 + lr) * 128 + ((kk * 64 + lg * 16) ^ rsw));
  };
  auto ldB = [&](int buf, int n, int kk) -> s8v {
    return *(const s8v*)((const char*)&Bs[buf][0] +
                         (wn * 64 + n * 16 + lr) * 128 + ((kk * 64 + lg * 16) ^ rsw));
  };

  f4v acc[4][4] = {};
  const int NT = Kloop >> 6;

  stageA(0, 0); stageB(0, 0);
  asm volatile("s_waitcnt vmcnt(0)" ::: "memory");
  __builtin_amdgcn_sched_barrier(0);
  __builtin_amdgcn_s_barrier();

  for (int t = 0; t < NT; ++t) {
    const int cb = t & 1, nb = cb ^ 1;
    if (t + 1 < NT) { stageA(t + 1, nb); stageB(t + 1, nb); }
    s8v af[2][4], bfr[2][4];
#pragma unroll
    for (int m = 0; m < 4; ++m) { af[0][m] = ldA(cb, m, 0); af[1][m] = ldA(cb, m, 1); }
#pragma unroll
    for (int n = 0; n < 4; ++n) { bfr[0][n] = ldB(cb, n, 0); bfr[1][n] = ldB(cb, n, 1); }
    __builtin_amdgcn_s_setprio(1);
#pragma unroll
    for (int m = 0; m < 4; ++m)
#pragma unroll
      for (int n = 0; n < 4; ++n) {
        acc[m][n] = __builtin_amdgcn_mfma_f32_16x16x32_bf16(af[0][m], bfr[0][n], acc[m][n], 0, 0, 0);
        acc[m][n] = __builtin_amdgcn_mfma_f32_16x16x32_bf16(af[1][m], bfr[1][n], acc[m][n], 0, 0, 0);
      }
    __builtin_amdgcn_s_setprio(0);
    if (t + 1 < NT) asm volatile("s_waitcnt vmcnt(0)" ::: "memory");
    __builtin_amdgcn_sched_barrier(0);
    __builtin_amdgcn_s_barrier();
  }

  ushort_t* Cp = (MODE == 2) ? (C + (size_t)ks * M * N) : C;
#pragma unroll
  for (int n = 0; n < 4; ++n) {
    int col = n0 + wn * 64 + n * 16 + lr;
    float bv = (MODE == 2) ? 0.f : bias[col];
    float sc = (MODE == 3 && col < DMODEL) ? QSCALE : 1.f;
#pragma unroll
    for (int m = 0; m < 4; ++m) {
      int row = m0 + wm * 64 + m * 16 + lg * 4;
#pragma unroll
      for (int j = 0; j < 4; ++j) {
        float v = acc[m][n][j] + bv;
        if (MODE == 1) v = fmaxf(v, 0.f);
        if (MODE == 3) v *= sc;
        Cp[(size_t)(row + j) * N + col] = f2bf(v);
      }
    }
  }
}

// ---------------- causal flash attention (v10: longest-first map + exp2) ----------------
// r15/r17 lessons: schemes that assume block->CU assignment (balanced map) or
// sacrifice residency (512-block pairing) both regress. Longest-first at
// grid 1024 (= exactly 4 blocks/CU resident) is the measured best (52.5us).
__global__ __launch_bounds__(256) void attn_kernel(const ushort_t* __restrict__ QKV,
                                                   const ushort_t* __restrict__ VT,
                                                   ushort_t* __restrict__ O) {
  const int bh = blockIdx.x;
  const int qt = 31 - (int)blockIdx.y;   // longest dispatched first
  const int b = bh >> 4, h = bh & 15;
  const int nkt = qt + 1;
  const int tid = threadIdx.x;
  const int w = tid >> 6, l = tid & 63;
  const int lr = l & 15, lg = l >> 4;

  __shared__ __align__(16) ushort_t Ksh[2][64 * 64];   // [k][d], chunk-swizzled
  __shared__ __align__(16) ushort_t Vsh[64 * 64];      // [d][k], single buffer
  __shared__ __align__(16) ushort_t Psh[4][16 * 72];   // per-wave [q][k], 144B rows

  const size_t RS = QKVN;
  const ushort_t* Qb = QKV + (size_t)b * TT * RS + h * 64;
  const ushort_t* Kb = Qb + DMODEL;
  const ushort_t* Vb = VT + (size_t)bh * 64 * TT;

  s8v qf[2];
  {
    const ushort_t* qr = Qb + (size_t)(qt * 64 + w * 16 + lr) * RS + lg * 8;
    qf[0] = *(const s8v*)qr;
    qf[1] = *(const s8v*)(qr + 32);
  }
  f4v acc[4] = {};
  float lrow = 0.f;

  const int sr8 = l >> 3, sc = l & 7;

  auto stageK = [&](int kt, int buf) {
#pragma unroll
    for (int s = 0; s < 2; ++s) {
      int r = s * 32 + w * 8 + sr8;
      gload16(Kb + (size_t)(kt * 64 + r) * RS + ((sc ^ (r & 7)) << 3),
              (char*)&Ksh[buf][0] + (s * 32 + w * 8) * 128 + l * 16);
    }
  };
  auto stageV = [&](int kt) {
#pragma unroll
    for (int s = 0; s < 2; ++s) {
      int r = s * 32 + w * 8 + sr8;
      gload16(Vb + (size_t)r * TT + kt * 64 + ((sc ^ (r & 7)) << 3),
              (char*)&Vsh[0] + (s * 32 + w * 8) * 128 + l * 16);
    }
  };

  stageK(0, 0);
  for (int kt = 0; kt < nkt; ++kt) {
    const int cb = kt & 1;
    const bool last = (kt + 1 >= nkt);
    stageV(kt);
    if (!last) {
      stageK(kt + 1, cb ^ 1);
      asm volatile("s_waitcnt vmcnt(4)" ::: "memory");   // K(kt) landed
    } else {
      asm volatile("s_waitcnt vmcnt(2)" ::: "memory");   // K(kt) landed
    }
    __builtin_amdgcn_sched_barrier(0);
    __builtin_amdgcn_s_barrier();

    // ---- QK^T (swapped: mfma(K,Q)) + exp2 + P staging (cvt_pk packing) ----
    float ps = 0.f;
#pragma unroll
    for (int c = 0; c < 4; ++c) {
      f4v a = {};
      __builtin_amdgcn_s_setprio(1);
#pragma unroll
      for (int kk = 0; kk < 2; ++kk) {
        int rr = c * 16 + lr;
        int byte_ = (rr * 128 + kk * 64 + lg * 16) ^ ((rr & 7) << 4);
        s8v kf = *(const s8v*)((const char*)&Ksh[cb][0] + byte_);
        a = __builtin_amdgcn_mfma_f32_16x16x32_bf16(kf, qf[kk], a, 0, 0, 0);
      }
      __builtin_amdgcn_s_setprio(0);
      float e[4];
#pragma unroll
      for (int j = 0; j < 4; ++j) {
        e[j] = exp2f(a[j]);   // Q pre-scaled by 0.125*log2(e)
        if (last && (c * 16 + lg * 4 + j > w * 16 + lr)) e[j] = 0.f;
        ps += e[j];
      }
      unsigned int pk0, pk1;
      asm("v_cvt_pk_bf16_f32 %0, %1, %2" : "=v"(pk0) : "v"(e[0]), "v"(e[1]));
      asm("v_cvt_pk_bf16_f32 %0, %1, %2" : "=v"(pk1) : "v"(e[2]), "v"(e[3]));
      *(uint2*)((char*)&Psh[w][0] + lr * 144 + (c * 16 + lg * 4) * 2) = make_uint2(pk0, pk1);
    }
    s8v pa[2];
    pa[0] = *(const s8v*)((const char*)&Psh[w][0] + lr * 144 + lg * 16);
    pa[1] = *(const s8v*)((const char*)&Psh[w][0] + lr * 144 + 64 + lg * 16);

    if (!last) {
      asm volatile("s_waitcnt vmcnt(2)" ::: "memory");   // V(kt) landed
    } else {
      asm volatile("s_waitcnt vmcnt(0)" ::: "memory");
    }
    __builtin_amdgcn_sched_barrier(0);
    __builtin_amdgcn_s_barrier();

    // ---- O += P @ V ----
    __builtin_amdgcn_s_setprio(1);
#pragma unroll
    for (int ks = 0; ks < 2; ++ks)
#pragma unroll
      for (int d = 0; d < 4; ++d) {
        int row = d * 16 + lr;
        int byte_ = (row * 128 + ks * 64 + lg * 16) ^ ((row & 7) << 4);
        s8v vf = *(const s8v*)((const char*)&Vsh[0] + byte_);
        acc[d] = __builtin_amdgcn_mfma_f32_16x16x32_bf16(pa[ks], vf, acc[d], 0, 0, 0);
      }
    __builtin_amdgcn_s_setprio(0);
    ps += __shfl_xor(ps, 16);
    ps += __shfl_xor(ps, 32);
    lrow += ps;
    __builtin_amdgcn_s_barrier();
  }

  float inv = 1.f / lrow;
  ushort_t* orow = O + ((size_t)b * TT + qt * 64 + w * 16) * DMODEL + h * 64;
#pragma unroll
  for (int j = 0; j < 4; ++j) {
    float invj = __shfl(inv, lg * 4 + j);
#pragma unroll
    for (int d = 0; d < 4; ++d)
      orow[(size_t)(lg * 4 + j) * DMODEL + d * 16 + lr] = f2bf(acc[d][j] * invj);
  }
}

// ---------------- LN 1: y_bf16 = LN(x_f32 + 2*attn_bf16) ----------------
__global__ __launch_bounds__(256) void ln_kernel(const float* __restrict__ aptr,
                                                 const ushort_t* __restrict__ bptr,
                                                 const float* __restrict__ g,
                                                 const float* __restrict__ be,
                                                 ushort_t* __restrict__ yptr) {
  const int row = blockIdx.x;
  const int t = threadIdx.x;
  const int w = t >> 6, l = t & 63;
  const size_t base = (size_t)row * DMODEL + t * 4;
  float v[4];
  us4v bb = *(const us4v*)(bptr + base);
  float4 xa = *(const float4*)(aptr + base);
  v[0] = xa.x + 2.f * bf2f(bb.x);
  v[1] = xa.y + 2.f * bf2f(bb.y);
  v[2] = xa.z + 2.f * bf2f(bb.z);
  v[3] = xa.w + 2.f * bf2f(bb.w);
  float s = v[0] + v[1] + v[2] + v[3];
  float s2 = v[0] * v[0] + v[1] * v[1] + v[2] * v[2] + v[3] * v[3];
#pragma unroll
  for (int off = 1; off <= 32; off <<= 1) {
    s += __shfl_xor(s, off);
    s2 += __shfl_xor(s2, off);
  }
  __shared__ float red[2][4];
  if (l == 0) { red[0][w] = s; red[1][w] = s2; }
  __syncthreads();
  s = red[0][0] + red[0][1] + red[0][2] + red[0][3];
  s2 = red[1][0] + red[1][1] + red[1][2] + red[1][3];
  const float mu = s * (1.f / 1024.f);
  const float var = s2 * (1.f / 1024.f) - mu * mu;
  const float rstd = rsqrtf(var + 1e-5f);
  float4 g4 = *(const float4*)(g + t * 4);
  float4 be4 = *(const float4*)(be + t * 4);
  us4v o;
  o.x = f2bf((v[0] - mu) * rstd * g4.x + be4.x);
  o.y = f2bf((v[1] - mu) * rstd * g4.y + be4.y);
  o.z = f2bf((v[2] - mu) * rstd * g4.z + be4.z);
  o.w = f2bf((v[3] - mu) * rstd * g4.w + be4.w);
  *(us4v*)(yptr + base) = o;
}

// ---------------- LN 2 (fused split-K=2 reduce): out = LN(x1 + 2*(SUMpart + b2)) ----------------
__global__ __launch_bounds__(256) void ln2_kernel(const ushort_t* __restrict__ x1,
                                                  const ushort_t* __restrict__ part,
                                                  const float* __restrict__ b2,
                                                  const float* __restrict__ g,
                                                  const float* __restrict__ be,
                                                  float* __restrict__ y) {
  const int row = blockIdx.x;
  const int t = threadIdx.x;
  const int w = t >> 6, l = t & 63;
  const size_t base = (size_t)row * DMODEL + t * 4;
  us4v xa = *(const us4v*)(x1 + base);
  float f[4] = {0.f, 0.f, 0.f, 0.f};
#pragma unroll
  for (int ks = 0; ks < 2; ++ks) {
    us4v p = *(const us4v*)(part + (size_t)ks * ROWS * DMODEL + base);
    f[0] += bf2f(p.x); f[1] += bf2f(p.y); f[2] += bf2f(p.z); f[3] += bf2f(p.w);
  }
  float4 b2v = *(const float4*)(b2 + t * 4);
  float v[4];
  v[0] = bf2f(xa.x) + 2.f * (f[0] + b2v.x);
  v[1] = bf2f(xa.y) + 2.f * (f[1] + b2v.y);
  v[2] = bf2f(xa.z) + 2.f * (f[2] + b2v.z);
  v[3] = bf2f(xa.w) + 2.f * (f[3] + b2v.w);
  float s = v[0] + v[1] + v[2] + v[3];
  float s2 = v[0] * v[0] + v[1] * v[1] + v[2] * v[2] + v[3] * v[3];
#pragma unroll
  for (int off = 1; off <= 32; off <<= 1) {
    s += __shfl_xor(s, off);
    s2 += __shfl_xor(s2, off);
  }
  __shared__ float red[2][4];
  if (l == 0) { red[0][w] = s; red[1][w] = s2; }
  __syncthreads();
  s = red[0][0] + red[0][1] + red[0][2] + red[0][3];
  s2 = red[1][0] + red[1][1] + red[1][2] + red[1][3];
  const float mu = s * (1.f / 1024.f);
  const float var = s2 * (1.f / 1024.f) - mu * mu;
  const float rstd = rsqrtf(var + 1e-5f);
  float4 g4 = *(const float4*)(g + t * 4);
  float4 be4 = *(const float4*)(be + t * 4);
  float4 o;
  o.x = (v[0] - mu) * rstd * g4.x + be4.x;
  o.y = (v[1] - mu) * rstd * g4.y + be4.y;
  o.z = (v[2] - mu) * rstd * g4.z + be4.z;
  o.w = (v[3] - mu) * rstd * g4.w + be4.w;
  *(float4*)(y + base) = o;
}

// ---------------- launch ----------------
extern "C" void kernel_launch(void* const* d_in, const int* in_sizes, int n_in,
                              void* d_out, int out_size, void* d_ws, size_t ws_size,
                              hipStream_t stream) {
  const float* x   = (const float*)d_in[0];
  const float* Wq  = (const float*)d_in[2];
  const float* bq  = (const float*)d_in[3];
  const float* Wk  = (const float*)d_in[4];
  const float* bk  = (const float*)d_in[5];
  const float* Wv  = (const float*)d_in[6];
  const float* bv  = (const float*)d_in[7];
  const float* W1  = (const float*)d_in[8];
  const float* b1  = (const float*)d_in[9];
  const float* W2  = (const float*)d_in[10];
  const float* b2  = (const float*)d_in[11];
  const float* g1  = (const float*)d_in[12];
  const float* be1 = (const float*)d_in[13];
  const float* g2  = (const float*)d_in[14];
  const float* be2 = (const float*)d_in[15];
  float* out = (float*)d_out;

  char* ws = (char*)d_ws;
  size_t off = 0;
  auto alloc = [&](size_t bytes) {
    char* p = ws + off;
    off += (bytes + 255) & ~(size_t)255;
    return p;
  };
  ushort_t* xb    = (ushort_t*)alloc((size_t)ROWS * DMODEL * 2);
  ushort_t* WqkvT = (ushort_t*)alloc((size_t)QKVN * DMODEL * 2);
  ushort_t* W1T   = (ushort_t*)alloc((size_t)DFF * DMODEL * 2);
  ushort_t* W2T   = (ushort_t*)alloc((size_t)DMODEL * DFF * 2);
  ushort_t* QKV   = (ushort_t*)alloc((size_t)ROWS * QKVN * 2);      // 24 MB
  ushort_t* VTb   = (ushort_t*)alloc((size_t)BB * NH * 64 * TT * 2); // 8 MB
  ushort_t* attnb = (ushort_t*)alloc((size_t)ROWS * DMODEL * 2);
  ushort_t* x1b   = (ushort_t*)alloc((size_t)ROWS * DMODEL * 2);
  ushort_t* H1b   = (ushort_t*)alloc((size_t)ROWS * DFF * 2);
  float* qkvb     = (float*)alloc(QKVN * 4);
  // FFN2 split-K=2 bf16 partials (2 x 8 MB) overlay dead QKV region.
  ushort_t* part  = QKV;
  (void)ws_size; (void)in_sizes; (void)n_in; (void)out_size;

  dim3 b256(256);
  dim3 tb(32, 8);
  cvt_f32_bf16<<<ROWS * DMODEL / 4 / 256, b256, 0, stream>>>(x, xb, ROWS * DMODEL / 4);
  trans_qkv<<<dim3(32, 32, 3), tb, 0, stream>>>(Wq, Wk, Wv, WqkvT);
  trans_ffn<<<dim3(DFF / 32, DMODEL / 32, 2), tb, 0, stream>>>(W1, W2, W1T, W2T);
  concat_bias<<<4, b256, 0, stream>>>(bq, bk, bv, qkvb);

  // QKV: 32 M-tiles x 24 N-tiles = 768 blocks; MODE 3 pre-scales Q cols
  gemm128<3><<<dim3(768), b256, 0, stream>>>(xb, WqkvT, qkvb, QKV,
                                             ROWS, QKVN, DMODEL, DMODEL,
                                             QKVN / 128, 768);
  vtrans<<<dim3(TT / 32, BB * NH), tb, 0, stream>>>(QKV, VTb);
  attn_kernel<<<dim3(BB * NH, 32), b256, 0, stream>>>(QKV, VTb, attnb);
  ln_kernel<<<ROWS, b256, 0, stream>>>(x, attnb, g1, be1, x1b);
  // FFN1: 32 x 32 = 1024 blocks
  gemm128<1><<<dim3(1024), b256, 0, stream>>>(x1b, W1T, b1, H1b,
                                              ROWS, DFF, DMODEL, DMODEL,
                                              DFF / 128, 1024);
  // FFN2: split-K=2 -> 32x8 tiles x 2 slices = 512 blocks; bf16 partials
  gemm128<2><<<dim3(512), b256, 0, stream>>>(H1b, W2T, b2, part,
                                             ROWS, DMODEL, DFF, DFF / 2,
                                             DMODEL / 128, 256);
  ln2_kernel<<<ROWS, b256, 0, stream>>>(x1b, part, b2, g2, be2, out);
}

// Round 19
// 212.009 us; speedup vs baseline: 1.0428x; 1.0126x over previous
//
#include <hip/hip_runtime.h>

#define DMODEL 1024
#define DKH 64
#define NH 16
#define DFF 4096
#define BB 2
#define TT 2048
#define ROWS (BB*TT)      // 4096
#define QKVN (3*DMODEL)   // 3072
#define QSCALE 0.18033688011112042f   // 0.125 * log2(e)

typedef unsigned short ushort_t;
typedef __attribute__((ext_vector_type(8))) short s8v;
typedef __attribute__((ext_vector_type(4))) float f4v;
typedef __attribute__((ext_vector_type(4))) unsigned short us4v;

typedef const void __attribute__((address_space(1)))* GPTR;
typedef void __attribute__((address_space(3)))* SPTR;

__device__ __forceinline__ float bf2f(ushort_t u) {
  return __uint_as_float(((unsigned int)u) << 16);
}
__device__ __forceinline__ ushort_t f2bf(float f) {
  unsigned int u = __float_as_uint(f);
  u += 0x7fffu + ((u >> 16) & 1u);
  return (ushort_t)(u >> 16);
}
__device__ __forceinline__ void gload16(const void* g, void* l) {
  __builtin_amdgcn_global_load_lds((GPTR)g, (SPTR)l, 16, 0, 0);
}

// ---------------- conversion kernels ----------------
__global__ __launch_bounds__(256) void cvt_f32_bf16(const float* __restrict__ in,
                                                    ushort_t* __restrict__ out, int n4) {
  int i = blockIdx.x * 256 + threadIdx.x;
  if (i >= n4) return;
  float4 v = ((const float4*)in)[i];
  us4v o;
  o.x = f2bf(v.x); o.y = f2bf(v.y); o.z = f2bf(v.z); o.w = f2bf(v.w);
  ((us4v*)out)[i] = o;
}

// Wq/Wk/Wv: three 1024x1024 f32 -> WqkvT [3][1024][1024] bf16 (transposed)
__global__ __launch_bounds__(256) void trans_qkv(const float* __restrict__ w0,
                                                 const float* __restrict__ w1,
                                                 const float* __restrict__ w2,
                                                 ushort_t* __restrict__ out) {
  __shared__ float tile[32][33];
  const float* in = (blockIdx.z == 0) ? w0 : (blockIdx.z == 1) ? w1 : w2;
  ushort_t* dst = out + (size_t)blockIdx.z * DMODEL * DMODEL;
  int bx = blockIdx.x * 32, by = blockIdx.y * 32;
  int tx = threadIdx.x, ty = threadIdx.y;
#pragma unroll
  for (int i = 0; i < 32; i += 8)
    tile[ty + i][tx] = in[(size_t)(by + ty + i) * DMODEL + bx + tx];
  __syncthreads();
#pragma unroll
  for (int i = 0; i < 32; i += 8)
    dst[(size_t)(bx + ty + i) * DMODEL + by + tx] = f2bf(tile[tx][ty + i]);
}

// W1 [1024,4096] -> W1T [4096,1024]; W2 [4096,1024] -> W2T [1024,4096]
__global__ __launch_bounds__(256) void trans_ffn(const float* __restrict__ W1,
                                                 const float* __restrict__ W2,
                                                 ushort_t* __restrict__ W1T,
                                                 ushort_t* __restrict__ W2T) {
  __shared__ float tile[32][33];
  const int z = blockIdx.z;
  const float* in = z ? W2 : W1;
  ushort_t* dst = z ? W2T : W1T;
  const int R = z ? DFF : DMODEL;      // in rows
  const int C = z ? DMODEL : DFF;      // in cols
  int bx = (z ? blockIdx.y : blockIdx.x) * 32;   // col-block
  int by = (z ? blockIdx.x : blockIdx.y) * 32;   // row-block
  int tx = threadIdx.x, ty = threadIdx.y;
#pragma unroll
  for (int i = 0; i < 32; i += 8)
    tile[ty + i][tx] = in[(size_t)(by + ty + i) * C + bx + tx];
  __syncthreads();
#pragma unroll
  for (int i = 0; i < 32; i += 8)
    dst[(size_t)(bx + ty + i) * R + by + tx] = f2bf(tile[tx][ty + i]);
}

__global__ void concat_bias(const float* __restrict__ a, const float* __restrict__ b,
                            const float* __restrict__ c, float* __restrict__ o) {
  int i = blockIdx.x * 256 + threadIdx.x;
  if (i < 1024) { o[i] = a[i]; o[1024 + i] = b[i]; o[2048 + i] = c[i]; }
}

// ---------------- GEMM 128x128, BK=64, dbuf, 1 barrier-pair/tile (r11-proven) ----------------
// MODE 0: +bias. MODE 1: +bias+relu. MODE 2: split-K partial (no bias).
// MODE 4: QKV-fused epilogue: +bias; Q cols (<1024) scaled by QSCALE;
//         V cols (>=2048) written TRANSPOSED into VT[bh][d][t] (replaces the
//         vtrans kernel; V never touches the QKV buffer). Blocks are 128-col
//         aligned and 2048 % 128 == 0, so the V branch is block-uniform.
template<int MODE>
__global__ __launch_bounds__(256) void gemm128(const ushort_t* __restrict__ A,
                                               const ushort_t* __restrict__ BT,
                                               const float* __restrict__ bias,
                                               ushort_t* __restrict__ C,
                                               ushort_t* __restrict__ VT,
                                               int M, int N, int Kstride, int Kloop,
                                               int nbx, int tiles_per_k) {
  __shared__ __align__(16) ushort_t As[2][128 * 64];   // 16 KB each
  __shared__ __align__(16) ushort_t Bs[2][128 * 64];
  const int nwg = gridDim.x;
  const int wg = blockIdx.x;
  const int cpx = nwg >> 3;                    // nwg % 8 == 0
  const int swz = (wg & 7) * cpx + (wg >> 3);  // XCD-aware (T1)
  const int ks = swz / tiles_per_k;
  const int tile = swz % tiles_per_k;
  const int bx = tile % nbx, by = tile / nbx;
  const int m0 = by * 128, n0 = bx * 128;
  const size_t kbase = (size_t)ks * Kloop;
  const int tid = threadIdx.x;
  const int w = tid >> 6, l = tid & 63, lr = l & 15, lg = l >> 4;
  const int wm = w >> 1, wn = w & 1;

  const int sr = tid >> 3;
  const int scol = (((tid & 7) ^ ((tid >> 3) & 7)) << 3);

  auto stageA = [&](int kt, int buf) {
#pragma unroll
    for (int s = 0; s < 4; ++s)
      gload16(A + (size_t)(m0 + s * 32 + sr) * Kstride + kbase + kt * 64 + scol,
              (char*)&As[buf][0] + s * 4096 + tid * 16);
  };
  auto stageB = [&](int kt, int buf) {
#pragma unroll
    for (int s = 0; s < 4; ++s)
      gload16(BT + (size_t)(n0 + s * 32 + sr) * Kstride + kbase + kt * 64 + scol,
              (char*)&Bs[buf][0] + s * 4096 + tid * 16);
  };

  const int rsw = (lr & 7) << 4;
  auto ldA = [&](int buf, int m, int kk) -> s8v {
    return *(const s8v*)((const char*)&As[buf][0] +
                         (wm * 64 + m * 16 + lr) * 128 + ((kk * 64 + lg * 16) ^ rsw));
  };
  auto ldB = [&](int buf, int n, int kk) -> s8v {
    return *(const s8v*)((const char*)&Bs[buf][0] +
                         (wn * 64 + n * 16 + lr) * 128 + ((kk * 64 + lg * 16) ^ rsw));
  };

  f4v acc[4][4] = {};
  const int NT = Kloop >> 6;

  stageA(0, 0); stageB(0, 0);
  asm volatile("s_waitcnt vmcnt(0)" ::: "memory");
  __builtin_amdgcn_sched_barrier(0);
  __builtin_amdgcn_s_barrier();

  for (int t = 0; t < NT; ++t) {
    const int cb = t & 1, nb = cb ^ 1;
    if (t + 1 < NT) { stageA(t + 1, nb); stageB(t + 1, nb); }
    s8v af[2][4], bfr[2][4];
#pragma unroll
    for (int m = 0; m < 4; ++m) { af[0][m] = ldA(cb, m, 0); af[1][m] = ldA(cb, m, 1); }
#pragma unroll
    for (int n = 0; n < 4; ++n) { bfr[0][n] = ldB(cb, n, 0); bfr[1][n] = ldB(cb, n, 1); }
    __builtin_amdgcn_s_setprio(1);
#pragma unroll
    for (int m = 0; m < 4; ++m)
#pragma unroll
      for (int n = 0; n < 4; ++n) {
        acc[m][n] = __builtin_amdgcn_mfma_f32_16x16x32_bf16(af[0][m], bfr[0][n], acc[m][n], 0, 0, 0);
        acc[m][n] = __builtin_amdgcn_mfma_f32_16x16x32_bf16(af[1][m], bfr[1][n], acc[m][n], 0, 0, 0);
      }
    __builtin_amdgcn_s_setprio(0);
    if (t + 1 < NT) asm volatile("s_waitcnt vmcnt(0)" ::: "memory");
    __builtin_amdgcn_sched_barrier(0);
    __builtin_amdgcn_s_barrier();
  }

  if (MODE == 4 && n0 >= 2 * DMODEL) {
    // V quadrant -> VT[bh][d][t]; 4 consecutive t per thread = one 8B store
    // (t = row & 2047 is a multiple of 4 by construction).
#pragma unroll
    for (int n = 0; n < 4; ++n) {
      int col = n0 + wn * 64 + n * 16 + lr;
      float bv = bias[col];
      int vcol = col - 2 * DMODEL;
      int hh = vcol >> 6, dd = vcol & 63;
#pragma unroll
      for (int m = 0; m < 4; ++m) {
        int row = m0 + wm * 64 + m * 16 + lg * 4;
        int bb = row >> 11, tt = row & 2047;
        us4v o;
        o.x = f2bf(acc[m][n][0] + bv);
        o.y = f2bf(acc[m][n][1] + bv);
        o.z = f2bf(acc[m][n][2] + bv);
        o.w = f2bf(acc[m][n][3] + bv);
        *(us4v*)(VT + ((size_t)(bb * NH + hh) * 64 + dd) * TT + tt) = o;
      }
    }
    return;
  }

  ushort_t* Cp = (MODE == 2) ? (C + (size_t)ks * M * N) : C;
#pragma unroll
  for (int n = 0; n < 4; ++n) {
    int col = n0 + wn * 64 + n * 16 + lr;
    float bv = (MODE == 2) ? 0.f : bias[col];
    float sc = (MODE == 4 && col < DMODEL) ? QSCALE : 1.f;
#pragma unroll
    for (int m = 0; m < 4; ++m) {
      int row = m0 + wm * 64 + m * 16 + lg * 4;
#pragma unroll
      for (int j = 0; j < 4; ++j) {
        float v = acc[m][n][j] + bv;
        if (MODE == 1) v = fmaxf(v, 0.f);
        if (MODE == 4) v *= sc;
        Cp[(size_t)(row + j) * N + col] = f2bf(v);
      }
    }
  }
}

// ---------------- causal flash attention (v10: longest-first map + exp2) ----------------
__global__ __launch_bounds__(256) void attn_kernel(const ushort_t* __restrict__ QKV,
                                                   const ushort_t* __restrict__ VT,
                                                   ushort_t* __restrict__ O) {
  const int bh = blockIdx.x;
  const int qt = 31 - (int)blockIdx.y;   // longest dispatched first
  const int b = bh >> 4, h = bh & 15;
  const int nkt = qt + 1;
  const int tid = threadIdx.x;
  const int w = tid >> 6, l = tid & 63;
  const int lr = l & 15, lg = l >> 4;

  __shared__ __align__(16) ushort_t Ksh[2][64 * 64];   // [k][d], chunk-swizzled
  __shared__ __align__(16) ushort_t Vsh[64 * 64];      // [d][k], single buffer
  __shared__ __align__(16) ushort_t Psh[4][16 * 72];   // per-wave [q][k], 144B rows

  const size_t RS = QKVN;
  const ushort_t* Qb = QKV + (size_t)b * TT * RS + h * 64;
  const ushort_t* Kb = Qb + DMODEL;
  const ushort_t* Vb = VT + (size_t)bh * 64 * TT;

  s8v qf[2];
  {
    const ushort_t* qr = Qb + (size_t)(qt * 64 + w * 16 + lr) * RS + lg * 8;
    qf[0] = *(const s8v*)qr;
    qf[1] = *(const s8v*)(qr + 32);
  }
  f4v acc[4] = {};
  float lrow = 0.f;

  const int sr8 = l >> 3, sc = l & 7;

  auto stageK = [&](int kt, int buf) {
#pragma unroll
    for (int s = 0; s < 2; ++s) {
      int r = s * 32 + w * 8 + sr8;
      gload16(Kb + (size_t)(kt * 64 + r) * RS + ((sc ^ (r & 7)) << 3),
              (char*)&Ksh[buf][0] + (s * 32 + w * 8) * 128 + l * 16);
    }
  };
  auto stageV = [&](int kt) {
#pragma unroll
    for (int s = 0; s < 2; ++s) {
      int r = s * 32 + w * 8 + sr8;
      gload16(Vb + (size_t)r * TT + kt * 64 + ((sc ^ (r & 7)) << 3),
              (char*)&Vsh[0] + (s * 32 + w * 8) * 128 + l * 16);
    }
  };

  stageK(0, 0);
  for (int kt = 0; kt < nkt; ++kt) {
    const int cb = kt & 1;
    const bool last = (kt + 1 >= nkt);
    stageV(kt);
    if (!last) {
      stageK(kt + 1, cb ^ 1);
      asm volatile("s_waitcnt vmcnt(4)" ::: "memory");   // K(kt) landed
    } else {
      asm volatile("s_waitcnt vmcnt(2)" ::: "memory");   // K(kt) landed
    }
    __builtin_amdgcn_sched_barrier(0);
    __builtin_amdgcn_s_barrier();

    // ---- QK^T (swapped: mfma(K,Q)) + exp2 + P staging (cvt_pk packing) ----
    float ps = 0.f;
#pragma unroll
    for (int c = 0; c < 4; ++c) {
      f4v a = {};
      __builtin_amdgcn_s_setprio(1);
#pragma unroll
      for (int kk = 0; kk < 2; ++kk) {
        int rr = c * 16 + lr;
        int byte_ = (rr * 128 + kk * 64 + lg * 16) ^ ((rr & 7) << 4);
        s8v kf = *(const s8v*)((const char*)&Ksh[cb][0] + byte_);
        a = __builtin_amdgcn_mfma_f32_16x16x32_bf16(kf, qf[kk], a, 0, 0, 0);
      }
      __builtin_amdgcn_s_setprio(0);
      float e[4];
#pragma unroll
      for (int j = 0; j < 4; ++j) {
        e[j] = exp2f(a[j]);   // Q pre-scaled by 0.125*log2(e)
        if (last && (c * 16 + lg * 4 + j > w * 16 + lr)) e[j] = 0.f;
        ps += e[j];
      }
      unsigned int pk0, pk1;
      asm("v_cvt_pk_bf16_f32 %0, %1, %2" : "=v"(pk0) : "v"(e[0]), "v"(e[1]));
      asm("v_cvt_pk_bf16_f32 %0, %1, %2" : "=v"(pk1) : "v"(e[2]), "v"(e[3]));
      *(uint2*)((char*)&Psh[w][0] + lr * 144 + (c * 16 + lg * 4) * 2) = make_uint2(pk0, pk1);
    }
    s8v pa[2];
    pa[0] = *(const s8v*)((const char*)&Psh[w][0] + lr * 144 + lg * 16);
    pa[1] = *(const s8v*)((const char*)&Psh[w][0] + lr * 144 + 64 + lg * 16);

    if (!last) {
      asm volatile("s_waitcnt vmcnt(2)" ::: "memory");   // V(kt) landed
    } else {
      asm volatile("s_waitcnt vmcnt(0)" ::: "memory");
    }
    __builtin_amdgcn_sched_barrier(0);
    __builtin_amdgcn_s_barrier();

    // ---- O += P @ V ----
    __builtin_amdgcn_s_setprio(1);
#pragma unroll
    for (int ks = 0; ks < 2; ++ks)
#pragma unroll
      for (int d = 0; d < 4; ++d) {
        int row = d * 16 + lr;
        int byte_ = (row * 128 + ks * 64 + lg * 16) ^ ((row & 7) << 4);
        s8v vf = *(const s8v*)((const char*)&Vsh[0] + byte_);
        acc[d] = __builtin_amdgcn_mfma_f32_16x16x32_bf16(pa[ks], vf, acc[d], 0, 0, 0);
      }
    __builtin_amdgcn_s_setprio(0);
    ps += __shfl_xor(ps, 16);
    ps += __shfl_xor(ps, 32);
    lrow += ps;
    __builtin_amdgcn_s_barrier();
  }

  float inv = 1.f / lrow;
  ushort_t* orow = O + ((size_t)b * TT + qt * 64 + w * 16) * DMODEL + h * 64;
#pragma unroll
  for (int j = 0; j < 4; ++j) {
    float invj = __shfl(inv, lg * 4 + j);
#pragma unroll
    for (int d = 0; d < 4; ++d)
      orow[(size_t)(lg * 4 + j) * DMODEL + d * 16 + lr] = f2bf(acc[d][j] * invj);
  }
}

// ---------------- LN 1: y_bf16 = LN(x_f32 + 2*attn_bf16) ----------------
__global__ __launch_bounds__(256) void ln_kernel(const float* __restrict__ aptr,
                                                 const ushort_t* __restrict__ bptr,
                                                 const float* __restrict__ g,
                                                 const float* __restrict__ be,
                                                 ushort_t* __restrict__ yptr) {
  const int row = blockIdx.x;
  const int t = threadIdx.x;
  const int w = t >> 6, l = t & 63;
  const size_t base = (size_t)row * DMODEL + t * 4;
  float v[4];
  us4v bb = *(const us4v*)(bptr + base);
  float4 xa = *(const float4*)(aptr + base);
  v[0] = xa.x + 2.f * bf2f(bb.x);
  v[1] = xa.y + 2.f * bf2f(bb.y);
  v[2] = xa.z + 2.f * bf2f(bb.z);
  v[3] = xa.w + 2.f * bf2f(bb.w);
  float s = v[0] + v[1] + v[2] + v[3];
  float s2 = v[0] * v[0] + v[1] * v[1] + v[2] * v[2] + v[3] * v[3];
#pragma unroll
  for (int off = 1; off <= 32; off <<= 1) {
    s += __shfl_xor(s, off);
    s2 += __shfl_xor(s2, off);
  }
  __shared__ float red[2][4];
  if (l == 0) { red[0][w] = s; red[1][w] = s2; }
  __syncthreads();
  s = red[0][0] + red[0][1] + red[0][2] + red[0][3];
  s2 = red[1][0] + red[1][1] + red[1][2] + red[1][3];
  const float mu = s * (1.f / 1024.f);
  const float var = s2 * (1.f / 1024.f) - mu * mu;
  const float rstd = rsqrtf(var + 1e-5f);
  float4 g4 = *(const float4*)(g + t * 4);
  float4 be4 = *(const float4*)(be + t * 4);
  us4v o;
  o.x = f2bf((v[0] - mu) * rstd * g4.x + be4.x);
  o.y = f2bf((v[1] - mu) * rstd * g4.y + be4.y);
  o.z = f2bf((v[2] - mu) * rstd * g4.z + be4.z);
  o.w = f2bf((v[3] - mu) * rstd * g4.w + be4.w);
  *(us4v*)(yptr + base) = o;
}

// ---------------- LN 2 (fused split-K=2 reduce): out = LN(x1 + 2*(SUMpart + b2)) ----------------
__global__ __launch_bounds__(256) void ln2_kernel(const ushort_t* __restrict__ x1,
                                                  const ushort_t* __restrict__ part,
                                                  const float* __restrict__ b2,
                                                  const float* __restrict__ g,
                                                  const float* __restrict__ be,
                                                  float* __restrict__ y) {
  const int row = blockIdx.x;
  const int t = threadIdx.x;
  const int w = t >> 6, l = t & 63;
  const size_t base = (size_t)row * DMODEL + t * 4;
  us4v xa = *(const us4v*)(x1 + base);
  float f[4] = {0.f, 0.f, 0.f, 0.f};
#pragma unroll
  for (int ks = 0; ks < 2; ++ks) {
    us4v p = *(const us4v*)(part + (size_t)ks * ROWS * DMODEL + base);
    f[0] += bf2f(p.x); f[1] += bf2f(p.y); f[2] += bf2f(p.z); f[3] += bf2f(p.w);
  }
  float4 b2v = *(const float4*)(b2 + t * 4);
  float v[4];
  v[0] = bf2f(xa.x) + 2.f * (f[0] + b2v.x);
  v[1] = bf2f(xa.y) + 2.f * (f[1] + b2v.y);
  v[2] = bf2f(xa.z) + 2.f * (f[2] + b2v.z);
  v[3] = bf2f(xa.w) + 2.f * (f[3] + b2v.w);
  float s = v[0] + v[1] + v[2] + v[3];
  float s2 = v[0] * v[0] + v[1] * v[1] + v[2] * v[2] + v[3] * v[3];
#pragma unroll
  for (int off = 1; off <= 32; off <<= 1) {
    s += __shfl_xor(s, off);
    s2 += __shfl_xor(s2, off);
  }
  __shared__ float red[2][4];
  if (l == 0) { red[0][w] = s; red[1][w] = s2; }
  __syncthreads();
  s = red[0][0] + red[0][1] + red[0][2] + red[0][3];
  s2 = red[1][0] + red[1][1] + red[1][2] + red[1][3];
  const float mu = s * (1.f / 1024.f);
  const float var = s2 * (1.f / 1024.f) - mu * mu;
  const float rstd = rsqrtf(var + 1e-5f);
  float4 g4 = *(const float4*)(g + t * 4);
  float4 be4 = *(const float4*)(be + t * 4);
  float4 o;
  o.x = (v[0] - mu) * rstd * g4.x + be4.x;
  o.y = (v[1] - mu) * rstd * g4.y + be4.y;
  o.z = (v[2] - mu) * rstd * g4.z + be4.z;
  o.w = (v[3] - mu) * rstd * g4.w + be4.w;
  *(float4*)(y + base) = o;
}

// ---------------- launch ----------------
extern "C" void kernel_launch(void* const* d_in, const int* in_sizes, int n_in,
                              void* d_out, int out_size, void* d_ws, size_t ws_size,
                              hipStream_t stream) {
  const float* x   = (const float*)d_in[0];
  const float* Wq  = (const float*)d_in[2];
  const float* bq  = (const float*)d_in[3];
  const float* Wk  = (const float*)d_in[4];
  const float* bk  = (const float*)d_in[5];
  const float* Wv  = (const float*)d_in[6];
  const float* bv  = (const float*)d_in[7];
  const float* W1  = (const float*)d_in[8];
  const float* b1  = (const float*)d_in[9];
  const float* W2  = (const float*)d_in[10];
  const float* b2  = (const float*)d_in[11];
  const float* g1  = (const float*)d_in[12];
  const float* be1 = (const float*)d_in[13];
  const float* g2  = (const float*)d_in[14];
  const float* be2 = (const float*)d_in[15];
  float* out = (float*)d_out;

  char* ws = (char*)d_ws;
  size_t off = 0;
  auto alloc = [&](size_t bytes) {
    char* p = ws + off;
    off += (bytes + 255) & ~(size_t)255;
    return p;
  };
  ushort_t* xb    = (ushort_t*)alloc((size_t)ROWS * DMODEL * 2);
  ushort_t* WqkvT = (ushort_t*)alloc((size_t)QKVN * DMODEL * 2);
  ushort_t* W1T   = (ushort_t*)alloc((size_t)DFF * DMODEL * 2);
  ushort_t* W2T   = (ushort_t*)alloc((size_t)DMODEL * DFF * 2);
  ushort_t* QKV   = (ushort_t*)alloc((size_t)ROWS * QKVN * 2);      // 24 MB
  ushort_t* VTb   = (ushort_t*)alloc((size_t)BB * NH * 64 * TT * 2); // 8 MB
  ushort_t* attnb = (ushort_t*)alloc((size_t)ROWS * DMODEL * 2);
  ushort_t* x1b   = (ushort_t*)alloc((size_t)ROWS * DMODEL * 2);
  ushort_t* H1b   = (ushort_t*)alloc((size_t)ROWS * DFF * 2);
  float* qkvb     = (float*)alloc(QKVN * 4);
  // FFN2 split-K=2 bf16 partials (2 x 8 MB) overlay dead QKV region.
  ushort_t* part  = QKV;
  (void)ws_size; (void)in_sizes; (void)n_in; (void)out_size;

  dim3 b256(256);
  dim3 tb(32, 8);
  cvt_f32_bf16<<<ROWS * DMODEL / 4 / 256, b256, 0, stream>>>(x, xb, ROWS * DMODEL / 4);
  trans_qkv<<<dim3(32, 32, 3), tb, 0, stream>>>(Wq, Wk, Wv, WqkvT);
  trans_ffn<<<dim3(DFF / 32, DMODEL / 32, 2), tb, 0, stream>>>(W1, W2, W1T, W2T);
  concat_bias<<<4, b256, 0, stream>>>(bq, bk, bv, qkvb);

  // QKV: 768 blocks; MODE 4 = bias + Q-scale + direct V-transpose to VTb
  gemm128<4><<<dim3(768), b256, 0, stream>>>(xb, WqkvT, qkvb, QKV, VTb,
                                             ROWS, QKVN, DMODEL, DMODEL,
                                             QKVN / 128, 768);
  attn_kernel<<<dim3(BB * NH, 32), b256, 0, stream>>>(QKV, VTb, attnb);
  ln_kernel<<<ROWS, b256, 0, stream>>>(x, attnb, g1, be1, x1b);
  // FFN1: 32 x 32 = 1024 blocks
  gemm128<1><<<dim3(1024), b256, 0, stream>>>(x1b, W1T, b1, H1b, nullptr,
                                              ROWS, DFF, DMODEL, DMODEL,
                                              DFF / 128, 1024);
  // FFN2: split-K=2 -> 32x8 tiles x 2 slices = 512 blocks; bf16 partials
  gemm128<2><<<dim3(512), b256, 0, stream>>>(H1b, W2T, b2, part, nullptr,
                                             ROWS, DMODEL, DFF, DFF / 2,
                                             DMODEL / 128, 256);
  ln2_kernel<<<ROWS, b256, 0, stream>>>(x1b, part, b2, g2, be2, out);
}

// Round 20
// 206.865 us; speedup vs baseline: 1.0688x; 1.0249x over previous
//
#include <hip/hip_runtime.h>

#define DMODEL 1024
#define DKH 64
#define NH 16
#define DFF 4096
#define BB 2
#define TT 2048
#define ROWS (BB*TT)      // 4096
#define QKVN (3*DMODEL)   // 3072
#define QSCALE 0.18033688011112042f   // 0.125 * log2(e)

typedef unsigned short ushort_t;
typedef __attribute__((ext_vector_type(8))) short s8v;
typedef __attribute__((ext_vector_type(4))) float f4v;
typedef __attribute__((ext_vector_type(4))) unsigned short us4v;

typedef const void __attribute__((address_space(1)))* GPTR;
typedef void __attribute__((address_space(3)))* SPTR;

__device__ __forceinline__ float bf2f(ushort_t u) {
  return __uint_as_float(((unsigned int)u) << 16);
}
__device__ __forceinline__ ushort_t f2bf(float f) {
  unsigned int u = __float_as_uint(f);
  u += 0x7fffu + ((u >> 16) & 1u);
  return (ushort_t)(u >> 16);
}
__device__ __forceinline__ void gload16(const void* g, void* l) {
  __builtin_amdgcn_global_load_lds((GPTR)g, (SPTR)l, 16, 0, 0);
}

// ---------------- fused prep: cvt(x) + trans(Wq/Wk/Wv) + trans(W1/W2) + bias concat ----------------
// Zones by blockIdx.x (all 256-thread, no inter-zone deps):
//   [0, 4096)            : x f32 -> xb bf16 (float4/thread)
//   [4096, 4096+3072)    : Wq/Wk/Wv 1024^2 transpose -> WqkvT
//   [7168, 7168+8192)    : W1 -> W1T, W2 -> W2T transpose
//   [15360, 15364)       : bias concat
__global__ __launch_bounds__(256) void prep(const float* __restrict__ x, ushort_t* __restrict__ xb,
                                            const float* __restrict__ Wq, const float* __restrict__ Wk,
                                            const float* __restrict__ Wv, ushort_t* __restrict__ WqkvT,
                                            const float* __restrict__ W1, const float* __restrict__ W2,
                                            ushort_t* __restrict__ W1T, ushort_t* __restrict__ W2T,
                                            const float* __restrict__ bq, const float* __restrict__ bk,
                                            const float* __restrict__ bv, float* __restrict__ qkvb) {
  __shared__ float tile[32][33];
  const int bid = blockIdx.x;
  const int tid = threadIdx.x;
  if (bid < 4096) {
    int i = bid * 256 + tid;
    float4 v = ((const float4*)x)[i];
    us4v o;
    o.x = f2bf(v.x); o.y = f2bf(v.y); o.z = f2bf(v.z); o.w = f2bf(v.w);
    ((us4v*)xb)[i] = o;
    return;
  }
  const int tx = tid & 31, ty = tid >> 5;   // (32,8)
  if (bid < 4096 + 3072) {
    int idx = bid - 4096;
    int z = idx >> 10, rem = idx & 1023;
    const float* in = (z == 0) ? Wq : (z == 1) ? Wk : Wv;
    ushort_t* dst = WqkvT + (size_t)z * DMODEL * DMODEL;
    int bx = (rem & 31) * 32, by = (rem >> 5) * 32;
#pragma unroll
    for (int i = 0; i < 32; i += 8)
      tile[ty + i][tx] = in[(size_t)(by + ty + i) * DMODEL + bx + tx];
    __syncthreads();
#pragma unroll
    for (int i = 0; i < 32; i += 8)
      dst[(size_t)(bx + ty + i) * DMODEL + by + tx] = f2bf(tile[tx][ty + i]);
    return;
  }
  if (bid < 4096 + 3072 + 8192) {
    int idx = bid - (4096 + 3072);
    int z = idx >> 12, rem = idx & 4095;
    const float* in = z ? W2 : W1;
    ushort_t* dst = z ? W2T : W1T;
    const int R = z ? DFF : DMODEL;
    const int C = z ? DMODEL : DFF;
    int cb = rem & 127, rb = rem >> 7;          // 128 x 32 decomposition
    int bx = (z ? rb : cb) * 32;                // col-block of input
    int by = (z ? cb : rb) * 32;                // row-block of input
#pragma unroll
    for (int i = 0; i < 32; i += 8)
      tile[ty + i][tx] = in[(size_t)(by + ty + i) * C + bx + tx];
    __syncthreads();
#pragma unroll
    for (int i = 0; i < 32; i += 8)
      dst[(size_t)(bx + ty + i) * R + by + tx] = f2bf(tile[tx][ty + i]);
    return;
  }
  {
    int i = (bid - (4096 + 3072 + 8192)) * 256 + tid;
    if (i < 1024) { qkvb[i] = bq[i]; qkvb[1024 + i] = bk[i]; qkvb[2048 + i] = bv[i]; }
  }
}

// ---------------- GEMM 128x128, BK=64, dbuf, 1 barrier-pair/tile (r11-proven) ----------------
// MODE 0: +bias. MODE 1: +bias+relu. MODE 2: split-K partial (no bias).
// MODE 4: QKV-fused epilogue: +bias; Q cols (<1024) scaled by QSCALE;
//         V cols (>=2048) written TRANSPOSED into VT[bh][d][t].
template<int MODE>
__global__ __launch_bounds__(256) void gemm128(const ushort_t* __restrict__ A,
                                               const ushort_t* __restrict__ BT,
                                               const float* __restrict__ bias,
                                               ushort_t* __restrict__ C,
                                               ushort_t* __restrict__ VT,
                                               int M, int N, int Kstride, int Kloop,
                                               int nbx, int tiles_per_k) {
  __shared__ __align__(16) ushort_t As[2][128 * 64];   // 16 KB each
  __shared__ __align__(16) ushort_t Bs[2][128 * 64];
  const int nwg = gridDim.x;
  const int wg = blockIdx.x;
  const int cpx = nwg >> 3;                    // nwg % 8 == 0
  const int swz = (wg & 7) * cpx + (wg >> 3);  // XCD-aware (T1)
  const int ks = swz / tiles_per_k;
  const int tile = swz % tiles_per_k;
  const int bx = tile % nbx, by = tile / nbx;
  const int m0 = by * 128, n0 = bx * 128;
  const size_t kbase = (size_t)ks * Kloop;
  const int tid = threadIdx.x;
  const int w = tid >> 6, l = tid & 63, lr = l & 15, lg = l >> 4;
  const int wm = w >> 1, wn = w & 1;

  const int sr = tid >> 3;
  const int scol = (((tid & 7) ^ ((tid >> 3) & 7)) << 3);

  auto stageA = [&](int kt, int buf) {
#pragma unroll
    for (int s = 0; s < 4; ++s)
      gload16(A + (size_t)(m0 + s * 32 + sr) * Kstride + kbase + kt * 64 + scol,
              (char*)&As[buf][0] + s * 4096 + tid * 16);
  };
  auto stageB = [&](int kt, int buf) {
#pragma unroll
    for (int s = 0; s < 4; ++s)
      gload16(BT + (size_t)(n0 + s * 32 + sr) * Kstride + kbase + kt * 64 + scol,
              (char*)&Bs[buf][0] + s * 4096 + tid * 16);
  };

  const int rsw = (lr & 7) << 4;
  auto ldA = [&](int buf, int m, int kk) -> s8v {
    return *(const s8v*)((const char*)&As[buf][0] +
                         (wm * 64 + m * 16 + lr) * 128 + ((kk * 64 + lg * 16) ^ rsw));
  };
  auto ldB = [&](int buf, int n, int kk) -> s8v {
    return *(const s8v*)((const char*)&Bs[buf][0] +
                         (wn * 64 + n * 16 + lr) * 128 + ((kk * 64 + lg * 16) ^ rsw));
  };

  f4v acc[4][4] = {};
  const int NT = Kloop >> 6;

  stageA(0, 0); stageB(0, 0);
  asm volatile("s_waitcnt vmcnt(0)" ::: "memory");
  __builtin_amdgcn_sched_barrier(0);
  __builtin_amdgcn_s_barrier();

  for (int t = 0; t < NT; ++t) {
    const int cb = t & 1, nb = cb ^ 1;
    if (t + 1 < NT) { stageA(t + 1, nb); stageB(t + 1, nb); }
    s8v af[2][4], bfr[2][4];
#pragma unroll
    for (int m = 0; m < 4; ++m) { af[0][m] = ldA(cb, m, 0); af[1][m] = ldA(cb, m, 1); }
#pragma unroll
    for (int n = 0; n < 4; ++n) { bfr[0][n] = ldB(cb, n, 0); bfr[1][n] = ldB(cb, n, 1); }
    __builtin_amdgcn_s_setprio(1);
#pragma unroll
    for (int m = 0; m < 4; ++m)
#pragma unroll
      for (int n = 0; n < 4; ++n) {
        acc[m][n] = __builtin_amdgcn_mfma_f32_16x16x32_bf16(af[0][m], bfr[0][n], acc[m][n], 0, 0, 0);
        acc[m][n] = __builtin_amdgcn_mfma_f32_16x16x32_bf16(af[1][m], bfr[1][n], acc[m][n], 0, 0, 0);
      }
    __builtin_amdgcn_s_setprio(0);
    if (t + 1 < NT) asm volatile("s_waitcnt vmcnt(0)" ::: "memory");
    __builtin_amdgcn_sched_barrier(0);
    __builtin_amdgcn_s_barrier();
  }

  if (MODE == 4 && n0 >= 2 * DMODEL) {
#pragma unroll
    for (int n = 0; n < 4; ++n) {
      int col = n0 + wn * 64 + n * 16 + lr;
      float bv = bias[col];
      int vcol = col - 2 * DMODEL;
      int hh = vcol >> 6, dd = vcol & 63;
#pragma unroll
      for (int m = 0; m < 4; ++m) {
        int row = m0 + wm * 64 + m * 16 + lg * 4;
        int bb = row >> 11, tt = row & 2047;
        us4v o;
        o.x = f2bf(acc[m][n][0] + bv);
        o.y = f2bf(acc[m][n][1] + bv);
        o.z = f2bf(acc[m][n][2] + bv);
        o.w = f2bf(acc[m][n][3] + bv);
        *(us4v*)(VT + ((size_t)(bb * NH + hh) * 64 + dd) * TT + tt) = o;
      }
    }
    return;
  }

  ushort_t* Cp = (MODE == 2) ? (C + (size_t)ks * M * N) : C;
#pragma unroll
  for (int n = 0; n < 4; ++n) {
    int col = n0 + wn * 64 + n * 16 + lr;
    float bv = (MODE == 2) ? 0.f : bias[col];
    float sc = (MODE == 4 && col < DMODEL) ? QSCALE : 1.f;
#pragma unroll
    for (int m = 0; m < 4; ++m) {
      int row = m0 + wm * 64 + m * 16 + lg * 4;
#pragma unroll
      for (int j = 0; j < 4; ++j) {
        float v = acc[m][n][j] + bv;
        if (MODE == 1) v = fmaxf(v, 0.f);
        if (MODE == 4) v *= sc;
        Cp[(size_t)(row + j) * N + col] = f2bf(v);
      }
    }
  }
}

// ---------------- causal flash attention (v10: longest-first map + exp2) ----------------
__global__ __launch_bounds__(256) void attn_kernel(const ushort_t* __restrict__ QKV,
                                                   const ushort_t* __restrict__ VT,
                                                   ushort_t* __restrict__ O) {
  const int bh = blockIdx.x;
  const int qt = 31 - (int)blockIdx.y;   // longest dispatched first
  const int b = bh >> 4, h = bh & 15;
  const int nkt = qt + 1;
  const int tid = threadIdx.x;
  const int w = tid >> 6, l = tid & 63;
  const int lr = l & 15, lg = l >> 4;

  __shared__ __align__(16) ushort_t Ksh[2][64 * 64];   // [k][d], chunk-swizzled
  __shared__ __align__(16) ushort_t Vsh[64 * 64];      // [d][k], single buffer
  __shared__ __align__(16) ushort_t Psh[4][16 * 72];   // per-wave [q][k], 144B rows

  const size_t RS = QKVN;
  const ushort_t* Qb = QKV + (size_t)b * TT * RS + h * 64;
  const ushort_t* Kb = Qb + DMODEL;
  const ushort_t* Vb = VT + (size_t)bh * 64 * TT;

  s8v qf[2];
  {
    const ushort_t* qr = Qb + (size_t)(qt * 64 + w * 16 + lr) * RS + lg * 8;
    qf[0] = *(const s8v*)qr;
    qf[1] = *(const s8v*)(qr + 32);
  }
  f4v acc[4] = {};
  float lrow = 0.f;

  const int sr8 = l >> 3, sc = l & 7;

  auto stageK = [&](int kt, int buf) {
#pragma unroll
    for (int s = 0; s < 2; ++s) {
      int r = s * 32 + w * 8 + sr8;
      gload16(Kb + (size_t)(kt * 64 + r) * RS + ((sc ^ (r & 7)) << 3),
              (char*)&Ksh[buf][0] + (s * 32 + w * 8) * 128 + l * 16);
    }
  };
  auto stageV = [&](int kt) {
#pragma unroll
    for (int s = 0; s < 2; ++s) {
      int r = s * 32 + w * 8 + sr8;
      gload16(Vb + (size_t)r * TT + kt * 64 + ((sc ^ (r & 7)) << 3),
              (char*)&Vsh[0] + (s * 32 + w * 8) * 128 + l * 16);
    }
  };

  stageK(0, 0);
  for (int kt = 0; kt < nkt; ++kt) {
    const int cb = kt & 1;
    const bool last = (kt + 1 >= nkt);
    stageV(kt);
    if (!last) {
      stageK(kt + 1, cb ^ 1);
      asm volatile("s_waitcnt vmcnt(4)" ::: "memory");   // K(kt) landed
    } else {
      asm volatile("s_waitcnt vmcnt(2)" ::: "memory");   // K(kt) landed
    }
    __builtin_amdgcn_sched_barrier(0);
    __builtin_amdgcn_s_barrier();

    // ---- QK^T (swapped: mfma(K,Q)) + exp2 + P staging (cvt_pk packing) ----
    float ps = 0.f;
#pragma unroll
    for (int c = 0; c < 4; ++c) {
      f4v a = {};
      __builtin_amdgcn_s_setprio(1);
#pragma unroll
      for (int kk = 0; kk < 2; ++kk) {
        int rr = c * 16 + lr;
        int byte_ = (rr * 128 + kk * 64 + lg * 16) ^ ((rr & 7) << 4);
        s8v kf = *(const s8v*)((const char*)&Ksh[cb][0] + byte_);
        a = __builtin_amdgcn_mfma_f32_16x16x32_bf16(kf, qf[kk], a, 0, 0, 0);
      }
      __builtin_amdgcn_s_setprio(0);
      float e[4];
#pragma unroll
      for (int j = 0; j < 4; ++j) {
        e[j] = exp2f(a[j]);   // Q pre-scaled by 0.125*log2(e)
        if (last && (c * 16 + lg * 4 + j > w * 16 + lr)) e[j] = 0.f;
        ps += e[j];
      }
      unsigned int pk0, pk1;
      asm("v_cvt_pk_bf16_f32 %0, %1, %2" : "=v"(pk0) : "v"(e[0]), "v"(e[1]));
      asm("v_cvt_pk_bf16_f32 %0, %1, %2" : "=v"(pk1) : "v"(e[2]), "v"(e[3]));
      *(uint2*)((char*)&Psh[w][0] + lr * 144 + (c * 16 + lg * 4) * 2) = make_uint2(pk0, pk1);
    }
    s8v pa[2];
    pa[0] = *(const s8v*)((const char*)&Psh[w][0] + lr * 144 + lg * 16);
    pa[1] = *(const s8v*)((const char*)&Psh[w][0] + lr * 144 + 64 + lg * 16);

    if (!last) {
      asm volatile("s_waitcnt vmcnt(2)" ::: "memory");   // V(kt) landed
    } else {
      asm volatile("s_waitcnt vmcnt(0)" ::: "memory");
    }
    __builtin_amdgcn_sched_barrier(0);
    __builtin_amdgcn_s_barrier();

    // ---- O += P @ V ----
    __builtin_amdgcn_s_setprio(1);
#pragma unroll
    for (int ks = 0; ks < 2; ++ks)
#pragma unroll
      for (int d = 0; d < 4; ++d) {
        int row = d * 16 + lr;
        int byte_ = (row * 128 + ks * 64 + lg * 16) ^ ((row & 7) << 4);
        s8v vf = *(const s8v*)((const char*)&Vsh[0] + byte_);
        acc[d] = __builtin_amdgcn_mfma_f32_16x16x32_bf16(pa[ks], vf, acc[d], 0, 0, 0);
      }
    __builtin_amdgcn_s_setprio(0);
    ps += __shfl_xor(ps, 16);
    ps += __shfl_xor(ps, 32);
    lrow += ps;
    __builtin_amdgcn_s_barrier();
  }

  float inv = 1.f / lrow;
  ushort_t* orow = O + ((size_t)b * TT + qt * 64 + w * 16) * DMODEL + h * 64;
#pragma unroll
  for (int j = 0; j < 4; ++j) {
    float invj = __shfl(inv, lg * 4 + j);
#pragma unroll
    for (int d = 0; d < 4; ++d)
      orow[(size_t)(lg * 4 + j) * DMODEL + d * 16 + lr] = f2bf(acc[d][j] * invj);
  }
}

// ---------------- LN 1: y_bf16 = LN(x_f32 + 2*attn_bf16) ----------------
__global__ __launch_bounds__(256) void ln_kernel(const float* __restrict__ aptr,
                                                 const ushort_t* __restrict__ bptr,
                                                 const float* __restrict__ g,
                                                 const float* __restrict__ be,
                                                 ushort_t* __restrict__ yptr) {
  const int row = blockIdx.x;
  const int t = threadIdx.x;
  const int w = t >> 6, l = t & 63;
  const size_t base = (size_t)row * DMODEL + t * 4;
  float v[4];
  us4v bb = *(const us4v*)(bptr + base);
  float4 xa = *(const float4*)(aptr + base);
  v[0] = xa.x + 2.f * bf2f(bb.x);
  v[1] = xa.y + 2.f * bf2f(bb.y);
  v[2] = xa.z + 2.f * bf2f(bb.z);
  v[3] = xa.w + 2.f * bf2f(bb.w);
  float s = v[0] + v[1] + v[2] + v[3];
  float s2 = v[0] * v[0] + v[1] * v[1] + v[2] * v[2] + v[3] * v[3];
#pragma unroll
  for (int off = 1; off <= 32; off <<= 1) {
    s += __shfl_xor(s, off);
    s2 += __shfl_xor(s2, off);
  }
  __shared__ float red[2][4];
  if (l == 0) { red[0][w] = s; red[1][w] = s2; }
  __syncthreads();
  s = red[0][0] + red[0][1] + red[0][2] + red[0][3];
  s2 = red[1][0] + red[1][1] + red[1][2] + red[1][3];
  const float mu = s * (1.f / 1024.f);
  const float var = s2 * (1.f / 1024.f) - mu * mu;
  const float rstd = rsqrtf(var + 1e-5f);
  float4 g4 = *(const float4*)(g + t * 4);
  float4 be4 = *(const float4*)(be + t * 4);
  us4v o;
  o.x = f2bf((v[0] - mu) * rstd * g4.x + be4.x);
  o.y = f2bf((v[1] - mu) * rstd * g4.y + be4.y);
  o.z = f2bf((v[2] - mu) * rstd * g4.z + be4.z);
  o.w = f2bf((v[3] - mu) * rstd * g4.w + be4.w);
  *(us4v*)(yptr + base) = o;
}

// ---------------- LN 2 (fused split-K=2 reduce): out = LN(x1 + 2*(SUMpart + b2)) ----------------
__global__ __launch_bounds__(256) void ln2_kernel(const ushort_t* __restrict__ x1,
                                                  const ushort_t* __restrict__ part,
                                                  const float* __restrict__ b2,
                                                  const float* __restrict__ g,
                                                  const float* __restrict__ be,
                                                  float* __restrict__ y) {
  const int row = blockIdx.x;
  const int t = threadIdx.x;
  const int w = t >> 6, l = t & 63;
  const size_t base = (size_t)row * DMODEL + t * 4;
  us4v xa = *(const us4v*)(x1 + base);
  float f[4] = {0.f, 0.f, 0.f, 0.f};
#pragma unroll
  for (int ks = 0; ks < 2; ++ks) {
    us4v p = *(const us4v*)(part + (size_t)ks * ROWS * DMODEL + base);
    f[0] += bf2f(p.x); f[1] += bf2f(p.y); f[2] += bf2f(p.z); f[3] += bf2f(p.w);
  }
  float4 b2v = *(const float4*)(b2 + t * 4);
  float v[4];
  v[0] = bf2f(xa.x) + 2.f * (f[0] + b2v.x);
  v[1] = bf2f(xa.y) + 2.f * (f[1] + b2v.y);
  v[2] = bf2f(xa.z) + 2.f * (f[2] + b2v.z);
  v[3] = bf2f(xa.w) + 2.f * (f[3] + b2v.w);
  float s = v[0] + v[1] + v[2] + v[3];
  float s2 = v[0] * v[0] + v[1] * v[1] + v[2] * v[2] + v[3] * v[3];
#pragma unroll
  for (int off = 1; off <= 32; off <<= 1) {
    s += __shfl_xor(s, off);
    s2 += __shfl_xor(s2, off);
  }
  __shared__ float red[2][4];
  if (l == 0) { red[0][w] = s; red[1][w] = s2; }
  __syncthreads();
  s = red[0][0] + red[0][1] + red[0][2] + red[0][3];
  s2 = red[1][0] + red[1][1] + red[1][2] + red[1][3];
  const float mu = s * (1.f / 1024.f);
  const float var = s2 * (1.f / 1024.f) - mu * mu;
  const float rstd = rsqrtf(var + 1e-5f);
  float4 g4 = *(const float4*)(g + t * 4);
  float4 be4 = *(const float4*)(be + t * 4);
  float4 o;
  o.x = (v[0] - mu) * rstd * g4.x + be4.x;
  o.y = (v[1] - mu) * rstd * g4.y + be4.y;
  o.z = (v[2] - mu) * rstd * g4.z + be4.z;
  o.w = (v[3] - mu) * rstd * g4.w + be4.w;
  *(float4*)(y + base) = o;
}

// ---------------- launch ----------------
extern "C" void kernel_launch(void* const* d_in, const int* in_sizes, int n_in,
                              void* d_out, int out_size, void* d_ws, size_t ws_size,
                              hipStream_t stream) {
  const float* x   = (const float*)d_in[0];
  const float* Wq  = (const float*)d_in[2];
  const float* bq  = (const float*)d_in[3];
  const float* Wk  = (const float*)d_in[4];
  const float* bk  = (const float*)d_in[5];
  const float* Wv  = (const float*)d_in[6];
  const float* bv  = (const float*)d_in[7];
  const float* W1  = (const float*)d_in[8];
  const float* b1  = (const float*)d_in[9];
  const float* W2  = (const float*)d_in[10];
  const float* b2  = (const float*)d_in[11];
  const float* g1  = (const float*)d_in[12];
  const float* be1 = (const float*)d_in[13];
  const float* g2  = (const float*)d_in[14];
  const float* be2 = (const float*)d_in[15];
  float* out = (float*)d_out;

  char* ws = (char*)d_ws;
  size_t off = 0;
  auto alloc = [&](size_t bytes) {
    char* p = ws + off;
    off += (bytes + 255) & ~(size_t)255;
    return p;
  };
  ushort_t* xb    = (ushort_t*)alloc((size_t)ROWS * DMODEL * 2);
  ushort_t* WqkvT = (ushort_t*)alloc((size_t)QKVN * DMODEL * 2);
  ushort_t* W1T   = (ushort_t*)alloc((size_t)DFF * DMODEL * 2);
  ushort_t* W2T   = (ushort_t*)alloc((size_t)DMODEL * DFF * 2);
  ushort_t* QKV   = (ushort_t*)alloc((size_t)ROWS * QKVN * 2);      // 24 MB
  ushort_t* VTb   = (ushort_t*)alloc((size_t)BB * NH * 64 * TT * 2); // 8 MB
  ushort_t* attnb = (ushort_t*)alloc((size_t)ROWS * DMODEL * 2);
  ushort_t* x1b   = (ushort_t*)alloc((size_t)ROWS * DMODEL * 2);
  ushort_t* H1b   = (ushort_t*)alloc((size_t)ROWS * DFF * 2);
  float* qkvb     = (float*)alloc(QKVN * 4);
  // FFN2 split-K=2 bf16 partials (2 x 8 MB) overlay dead QKV region.
  ushort_t* part  = QKV;
  (void)ws_size; (void)in_sizes; (void)n_in; (void)out_size;

  dim3 b256(256);
  // fused prep: 4096 (cvt) + 3072 (Wqkv) + 8192 (W1/W2) + 4 (bias) blocks
  prep<<<dim3(4096 + 3072 + 8192 + 4), b256, 0, stream>>>(
      x, xb, Wq, Wk, Wv, WqkvT, W1, W2, W1T, W2T, bq, bk, bv, qkvb);

  // QKV: 768 blocks; MODE 4 = bias + Q-scale + direct V-transpose to VTb
  gemm128<4><<<dim3(768), b256, 0, stream>>>(xb, WqkvT, qkvb, QKV, VTb,
                                             ROWS, QKVN, DMODEL, DMODEL,
                                             QKVN / 128, 768);
  attn_kernel<<<dim3(BB * NH, 32), b256, 0, stream>>>(QKV, VTb, attnb);
  ln_kernel<<<ROWS, b256, 0, stream>>>(x, attnb, g1, be1, x1b);
  // FFN1: 32 x 32 = 1024 blocks
  gemm128<1><<<dim3(1024), b256, 0, stream>>>(x1b, W1T, b1, H1b, nullptr,
                                              ROWS, DFF, DMODEL, DMODEL,
                                              DFF / 128, 1024);
  // FFN2: split-K=2 -> 32x8 tiles x 2 slices = 512 blocks; bf16 partials
  gemm128<2><<<dim3(512), b256, 0, stream>>>(H1b, W2T, b2, part, nullptr,
                                             ROWS, DMODEL, DFF, DFF / 2,
                                             DMODEL / 128, 256);
  ln2_kernel<<<ROWS, b256, 0, stream>>>(x1b, part, b2, g2, be2, out);
}